// Round 1
// 3840.427 us; speedup vs baseline: 1.5621x; 1.5621x over previous
//
#include <hip/hip_runtime.h>
#include <cstdint>
#include <cstddef>

#define DEV __device__ __forceinline__
typedef short bf16x8 __attribute__((ext_vector_type(8)));
typedef float fl4 __attribute__((ext_vector_type(4)));
typedef float f32x4 __attribute__((ext_vector_type(4)));
typedef unsigned short u16;

#define BN_INV 0.9999950000375f

DEV float b2f(u16 u){ return __uint_as_float(((unsigned)u)<<16); }
DEV u16 f2b(float f){ unsigned u = __float_as_uint(f); unsigned r = (u + 0x7FFFu + ((u>>16)&1u))>>16; return (u16)r; }

DEV bf16x8 load8(const u16* p){ return *(const bf16x8*)p; }
DEV bf16x8 load8(const float* p){
  fl4 a = *(const fl4*)p; fl4 b = *(const fl4*)(p+4);
  bf16x8 r;
  r[0]=(short)f2b(a[0]); r[1]=(short)f2b(a[1]); r[2]=(short)f2b(a[2]); r[3]=(short)f2b(a[3]);
  r[4]=(short)f2b(b[0]); r[5]=(short)f2b(b[1]); r[6]=(short)f2b(b[2]); r[7]=(short)f2b(b[3]);
  return r;
}

// ---------------------------------------------------------------- pack kernels

// frames [192][512][49] f32 -> XT [192*64][512] bf16 (rows p>=49 zero)
__global__ __launch_bounds__(256) void k_pack_frames(const float* __restrict__ fr, u16* __restrict__ XT){
  int bt = blockIdx.x, tid = threadIdx.x;
  for (int e=0;e<128;e++){
    int flat = e*256 + tid;           // < 32768
    int p = flat>>9, c = flat&511;
    u16 v = 0;
    if (p < 49) v = f2b(fr[((size_t)bt*512 + c)*49 + p]);
    XT[((size_t)bt*64 + p)*512 + c] = v;
  }
}

// wseq [4096][2176] bf16 = [w_hh | w_ih cols 2500:3652]
__global__ __launch_bounds__(256) void k_pack_wseq(const float* __restrict__ w_ih, const float* __restrict__ w_hh,
                                                   u16* __restrict__ wseq){
  int r = blockIdx.x, tid = threadIdx.x;
  const float* wr = w_ih + (size_t)r*4164;
  for (int j=tid;j<2176;j+=256){
    float v = (j < 1024) ? w_hh[(size_t)r*1024 + j] : wr[2500 + (j-1024)];
    wseq[(size_t)r*2176 + j] = f2b(v);
  }
}

// dseq [3264][2176] bf16 = [dw cols 0:1024 | dw cols 3524:4676]  (rows 0:3136 d1_w, then actor_w)
__global__ __launch_bounds__(256) void k_pack_dseq(const float* __restrict__ d1_w, const float* __restrict__ actor_w,
                                                   u16* __restrict__ dseq){
  int r = blockIdx.x, tid = threadIdx.x;
  const float* wr = (r < 3136) ? (d1_w + (size_t)r*5188) : (actor_w + (size_t)(r-3136)*5188);
  for (int j=tid;j<2176;j+=256){
    float v = (j < 1024) ? wr[j] : wr[3524 + (j-1024)];
    dseq[(size_t)r*2176 + j] = f2b(v);
  }
}

// wvg chunk [1024][3072] bf16 = [w_ih cols 0:2500 | w_ih cols 3652:4164 | 0]
__global__ __launch_bounds__(256) void k_pack_wvg(const float* __restrict__ w_ih, u16* __restrict__ wvg, int rbase){
  int r = rbase + blockIdx.x, tid = threadIdx.x;
  const float* wr = w_ih + (size_t)r*4164;
  u16* dst = wvg + (size_t)blockIdx.x*3072;
  for (int j=tid;j<3072;j+=256){
    float v = 0.f;
    if (j < 2500) v = wr[j];
    else if (j < 3012) v = wr[3652 + (j-2500)];
    dst[j] = f2b(v);
  }
}

// dvg chunk [1088][3072] bf16 = [dw cols 1024:3524 | dw cols 4676:5188 | 0]
__global__ __launch_bounds__(256) void k_pack_dvg(const float* __restrict__ d1_w, const float* __restrict__ actor_w,
                                                  u16* __restrict__ dvg, int rbase){
  int r = rbase + blockIdx.x, tid = threadIdx.x;
  const float* wr = (r < 3136) ? (d1_w + (size_t)r*5188) : (actor_w + (size_t)(r-3136)*5188);
  u16* dst = dvg + (size_t)blockIdx.x*3072;
  for (int j=tid;j<3072;j+=256){
    float v = 0.f;
    if (j < 2500) v = wr[1024 + j];
    else if (j < 3012) v = wr[4676 + (j-2500)];
    dst[j] = f2b(v);
  }
}

__global__ __launch_bounds__(256) void k_hfcT(const float* __restrict__ hfc_w, u16* __restrict__ hfcT){
  int idx = blockIdx.x*256 + threadIdx.x;   // 1M
  int k = idx>>10, o = idx&1023;
  hfcT[idx] = f2b(hfc_w[o*1024 + k]);
}

DEV u16 wt_map(const float* w, int n, int k, int CIN, int COUT){
  int o = n % COUT; int cls = n / COUT;
  if (cls >= 4) return 0;
  int py = cls>>1, px = cls&1;
  int i = k/9; int dd = k - i*9; int dy = dd/3, dx = dd - dy*3;
  if (i >= CIN) return 0;
  int ky = (py==0) ? (dy==0 ? 3 : (dy==1 ? 1 : -1)) : (dy==1 ? 2 : (dy==2 ? 0 : -1));
  int kx = (px==0) ? (dx==0 ? 3 : (dx==1 ? 1 : -1)) : (dx==1 ? 2 : (dx==2 ? 0 : -1));
  if (ky < 0 || kx < 0) return 0;
  return f2b(w[((i*COUT + o)*4 + ky)*4 + kx]);
}

__global__ __launch_bounds__(256) void k_misc(
  const float* b_ih, const float* b_hh, const float* d1_b, const float* actor_b,
  const float* emb_w, const float* h0, const float* c0,
  const float* dw3, const float* dw2, const float* dw1,
  float* bias_g, float* bias_da, u16* embT, float* hb0, float* cws,
  u16* Wt3, u16* Wt2, u16* Wt1)
{
  int blk = blockIdx.x, tid = threadIdx.x;
  if (blk < 16){ int i = blk*256+tid; if (i<4096) bias_g[i] = b_ih[i] + b_hh[i]; }
  else if (blk < 29){ int i = (blk-16)*256+tid; if (i<3264) bias_da[i] = (i<3136)? d1_b[i] : actor_b[i-3136]; }
  else if (blk < 541){ int i = (blk-29)*256+tid; int j = i>>10, v = i&1023; embT[i] = f2b(emb_w[v*128 + j]); }
  else if (blk < 573){ int i = (blk-541)*256+tid; if (i<8192){ hb0[i] = h0[i]; cws[i] = c0[i]; } }
  else if (blk < 574){ for (int i=tid;i<2560;i+=256){ int n=i/160, k=i-n*160; Wt1[i] = wt_map(dw1,n,k,16,1); } }
  else if (blk < 590){ for (int i=(blk-574)*256+tid; i<18432; i+=16*256){ int n=i/288, k=i-n*288; Wt2[i] = wt_map(dw2,n,k,32,16); } }
  else { for (int i=(blk-590)*256+tid; i<73728; i+=168*256){ int n=i/576, k=i-n*576; Wt3[i] = wt_map(dw3,n,k,64,32); } }
}

__global__ __launch_bounds__(256) void k_eb(const float* __restrict__ enc, const float* __restrict__ hfc_b, float* __restrict__ eb){
  int li = blockIdx.x*4 + (threadIdx.x>>6);
  int lane = threadIdx.x & 63;
  if (li >= 1160) return;
  const float* ep = enc + (size_t)li*1024;
  float a = 0.f;
  for (int k=lane;k<1024;k+=64) a += ep[k]*hfc_b[k];
  #pragma unroll
  for (int off=32; off; off>>=1) a += __shfl_xor(a, off);
  if (lane == 0) eb[li] = a;
}

// Y2 [192*64][64] bf16 -> vis_in [192][3136] bf16 (c*49+p ordering)
__global__ __launch_bounds__(256) void k_vis_in(const u16* __restrict__ Y2, u16* __restrict__ vis_in){
  int bt = blockIdx.x, tid = threadIdx.x;
  for (int f=tid; f<3136; f+=256){
    int c = f/49, p = f - c*49;
    vis_in[(size_t)bt*3136 + f] = Y2[((size_t)bt*64 + p)*64 + c];
  }
}

// xin2 [192][3072] bf16 = [vis 2500 | gcn 512 | 0]
__global__ __launch_bounds__(256) void k_xin(const u16* __restrict__ vis, const float* __restrict__ gcn, u16* __restrict__ xin2){
  int bt = blockIdx.x, tid = threadIdx.x, b = bt/24;
  for (int j=tid;j<3072;j+=256){
    u16 v = 0;
    if (j < 2500) v = vis[(size_t)bt*2500 + j];
    else if (j < 3012) v = f2b(gcn[b*512 + (j-2500)]);
    xin2[(size_t)bt*3072 + j] = v;
  }
}

// ---------------------------------------------------------------- generic MFMA GEMM (C[M,N] = A[M,K] @ B[N,K]^T)
template<int OUTB, int ACT, typename TA, typename TB>
__global__ __launch_bounds__(256) void gemm64(
  const TA* __restrict__ A, int lda, const TB* __restrict__ Bm, int ldb,
  void* __restrict__ Cv, int ldc, int M, int N, int K,
  const float* __restrict__ bias, const float* __restrict__ cb, const float* __restrict__ gg, const float* __restrict__ bb)
{
  __shared__ u16 sA[64*72];
  __shared__ u16 sB[64*72];
  int tid = threadIdx.x, lane = tid & 63, w = tid >> 6;
  int wm = w & 1, wn = w >> 1;
  int m0 = blockIdx.x*64, n0 = blockIdx.y*64;
  f32x4 acc[2][2];
  #pragma unroll
  for (int a=0;a<2;a++)
    #pragma unroll
    for (int b=0;b<2;b++){ acc[a][b][0]=0;acc[a][b][1]=0;acc[a][b][2]=0;acc[a][b][3]=0; }

  for (int k0=0;k0<K;k0+=64){
    #pragma unroll
    for (int j=0;j<2;j++){
      int c = tid + 256*j; int row = c>>3; int col = (c&7)*8;
      bf16x8 va = {0,0,0,0,0,0,0,0};
      int gm = m0 + row;
      if (gm < M) va = load8(A + (size_t)gm*lda + k0 + col);
      *(bf16x8*)(&sA[row*72 + col]) = va;
      bf16x8 vb = {0,0,0,0,0,0,0,0};
      int gn = n0 + row;
      if (gn < N) vb = load8(Bm + (size_t)gn*ldb + k0 + col);
      *(bf16x8*)(&sB[row*72 + col]) = vb;
    }
    __syncthreads();
    #pragma unroll
    for (int kk=0;kk<2;kk++){
      bf16x8 af[2], bfv[2];
      #pragma unroll
      for (int tm=0;tm<2;tm++) af[tm]  = *(const bf16x8*)(&sA[(wm*32+tm*16+(lane&15))*72 + kk*32 + (lane>>4)*8]);
      #pragma unroll
      for (int tn=0;tn<2;tn++) bfv[tn] = *(const bf16x8*)(&sB[(wn*32+tn*16+(lane&15))*72 + kk*32 + (lane>>4)*8]);
      #pragma unroll
      for (int tm=0;tm<2;tm++)
        #pragma unroll
        for (int tn=0;tn<2;tn++)
          acc[tm][tn] = __builtin_amdgcn_mfma_f32_16x16x32_bf16(af[tm], bfv[tn], acc[tm][tn], 0,0,0);
    }
    __syncthreads();
  }
  int ml = (lane>>4)*4, nl = lane&15;
  #pragma unroll
  for (int tm=0;tm<2;tm++)
    #pragma unroll
    for (int tn=0;tn<2;tn++)
      #pragma unroll
      for (int r=0;r<4;r++){
        int gm = m0 + wm*32 + tm*16 + ml + r;
        int gn = n0 + wn*32 + tn*16 + nl;
        if (gm < M && gn < N){
          float v = acc[tm][tn][r];
          if (ACT == 0){ if (bias) v += bias[gn]; }
          else { v = (v + cb[gn])*BN_INV*gg[gn] + bb[gn]; v = fmaxf(v, 0.f); }
          if (OUTB) ((u16*)Cv)[(size_t)gm*ldc + gn] = f2b(v);
          else      ((float*)Cv)[(size_t)gm*ldc + gn] = v;
        }
      }
}

// ---------------------------------------------------------------- per-step kernels

// P1: scores (blocks 0-39) + action/argmax of t-1 (40-71) + h/c output at t==24 (72-79)
__global__ __launch_bounds__(256) void p1_scores_action(
  const float* __restrict__ encH, const float* __restrict__ eb,
  const float* __restrict__ hcur, const float* __restrict__ cws,
  float* __restrict__ scores, const float* __restrict__ d1a_out,
  const u16* __restrict__ embT, float* __restrict__ out_act,
  float* __restrict__ cmv, int* __restrict__ cmi,
  float* __restrict__ out_h, float* __restrict__ out_c, int t)
{
  __shared__ float shf[1024];
  __shared__ int shi[256];
  int blk = blockIdx.x, tid = threadIdx.x;
  if (blk < 40){
    if (t == 24) return;
    int b = blk/5, lc = blk - b*5;
    #pragma unroll
    for (int e=0;e<4;e++) shf[tid + 256*e] = hcur[b*1024 + tid + 256*e];
    __syncthreads();
    int w = tid>>6, lane = tid&63;
    for (int i=w;i<29;i+=4){
      int l = lc*29 + i;
      const float* ep = encH + (size_t)(b*145+l)*1024;
      float a = 0.f;
      for (int k=lane;k<1024;k+=64) a += ep[k]*shf[k];
      #pragma unroll
      for (int off=32; off; off>>=1) a += __shfl_xor(a, off);
      if (lane == 0) scores[b*145+l] = a + eb[b*145+l];
    }
  } else if (blk < 72){
    if (t == 0) return;
    int idx = blk-40; int b = idx>>2, vc = idx&3;
    if (tid < 128) shf[tid] = d1a_out[(size_t)(b*24 + t-1)*3264 + 3136 + tid];
    __syncthreads();
    int v = vc*256 + tid;
    float a = 0.f;
    for (int j=0;j<128;j++) a += shf[j]*b2f(embT[j*1024 + v]);
    out_act[(size_t)(b*24 + t-1)*1024 + v] = a;
    shf[256+tid] = a; shi[tid] = v;
    __syncthreads();
    for (int s=128; s; s>>=1){
      if (tid < s){
        float o = shf[256+tid+s]; int oi = shi[tid+s];
        float c = shf[256+tid];   int ci = shi[tid];
        if (o > c || (o == c && oi < ci)){ shf[256+tid] = o; shi[tid] = oi; }
      }
      __syncthreads();
    }
    if (tid == 0){ cmv[b*4+vc] = shf[256]; cmi[b*4+vc] = shi[0]; }
  } else {
    if (t != 24) return;
    int b = blk-72;
    #pragma unroll
    for (int e=0;e<4;e++){
      int k = tid + 256*e;
      out_h[b*1024+k] = hcur[b*1024+k];
      out_c[b*1024+k] = cws[b*1024+k];
    }
  }
}

// P2: softmax + weighted + attn-out + e selection
__global__ __launch_bounds__(256) void p2_softmax_weighted(
  const float* __restrict__ scores, const float* __restrict__ enc,
  float* __restrict__ wgt, float* __restrict__ ecur,
  const float* __restrict__ cmv, const int* __restrict__ cmi,
  const float* __restrict__ emb_w, const float* __restrict__ go,
  float* __restrict__ out_attn, int t)
{
  int b = blockIdx.x >> 3, dc = blockIdx.x & 7, tid = threadIdx.x;
  __shared__ float s[145];
  __shared__ float mxs, invs;
  if (tid < 145) s[tid] = scores[b*145+tid];
  __syncthreads();
  if (tid < 64){
    float m = -1e30f;
    for (int i=tid;i<145;i+=64) m = fmaxf(m, s[i]);
    #pragma unroll
    for (int off=32; off; off>>=1) m = fmaxf(m, __shfl_xor(m, off));
    if (tid == 0) mxs = m;
  }
  __syncthreads();
  if (tid < 145) s[tid] = expf(s[tid]-mxs);
  __syncthreads();
  if (tid < 64){
    float sm = 0.f;
    for (int i=tid;i<145;i+=64) sm += s[i];
    #pragma unroll
    for (int off=32; off; off>>=1) sm += __shfl_xor(sm, off);
    if (tid == 0) invs = 1.f/sm;
  }
  __syncthreads();
  float inv = invs;
  if (tid < 128){
    int d = dc*128 + tid;
    float a = 0.f;
    for (int l=0;l<145;l++) a += s[l]*enc[(size_t)(b*145+l)*1024 + d];
    wgt[b*1024+d] = a*inv;
  } else {
    int i = tid-128;
    if (dc == 0){
      if (i < 145) out_attn[(size_t)(b*24+t)*145 + i] = s[i]*inv;
      int l2 = i + 128;
      if (l2 < 145) out_attn[(size_t)(b*24+t)*145 + l2] = s[l2]*inv;
    } else if (dc == 1){
      if (t == 0) ecur[b*128+i] = go[i];
      else {
        float bv = cmv[b*4]; int bi = cmi[b*4];
        #pragma unroll
        for (int c=1;c<4;c++){
          float v2 = cmv[b*4+c]; int i2 = cmi[b*4+c];
          if (v2 > bv || (v2 == bv && i2 < bi)){ bv = v2; bi = i2; }
        }
        ecur[b*128+i] = emb_w[bi*128 + i];
      }
    }
  }
}

DEV void stage_sin(u16* sA, const float* hvec, const float* wgt, const float* ecur, int tid){
  for (int e=0;e<68;e++){
    int flat = e*256 + tid;           // exactly 8*2176
    int b = flat/2176; int k = flat - b*2176;
    float v = (k < 1024) ? hvec[b*1024+k] : (k < 2048 ? wgt[b*1024 + (k-1024)] : ecur[b*128 + (k-2048)]);
    sA[b*2184 + k] = f2b(v);
  }
}

// P3: gates (sequential part, K=2176) + fused LSTM
__global__ __launch_bounds__(256) void p3_gates_lstm(
  const u16* __restrict__ wseq, const float* __restrict__ gpre,
  const float* __restrict__ hprev, float* __restrict__ hnew, float* __restrict__ cws,
  const float* __restrict__ wgt, const float* __restrict__ ecur, int t)
{
  __shared__ u16 sA[8*2184];
  __shared__ float gl[512];
  int tid = threadIdx.x;
  stage_sin(sA, hprev, wgt, ecur, tid);
  __syncthreads();
  int lane = tid & 63, g = tid >> 6;
  int n = g*1024 + blockIdx.x*16 + (lane & 15);
  const u16* bp = wseq + (size_t)n*2176 + ((lane>>4)*8);
  int aoff = (lane&7)*2184 + ((lane>>4)*8);
  f32x4 acc = {0,0,0,0};
  #pragma unroll 8
  for (int kk=0;kk<68;kk++){
    bf16x8 a = *(const bf16x8*)(&sA[aoff + kk*32]);
    bf16x8 b = *(const bf16x8*)(bp + kk*32);
    acc = __builtin_amdgcn_mfma_f32_16x16x32_bf16(a, b, acc, 0,0,0);
  }
  #pragma unroll
  for (int r=0;r<4;r++){
    int m = (lane>>4)*4 + r;
    if (m < 8) gl[(g*16 + (lane&15))*8 + m] = acc[r];
  }
  __syncthreads();
  if (tid < 128){
    int j = tid>>3, b = tid&7; int J = blockIdx.x*16 + j;
    const float* gp = gpre + (size_t)(b*24+t)*4096;
    float iv = gl[(0*16+j)*8+b] + gp[J];
    float fv = gl[(1*16+j)*8+b] + gp[1024+J];
    float gv = gl[(2*16+j)*8+b] + gp[2048+J];
    float ov = gl[(3*16+j)*8+b] + gp[3072+J];
    float ig = 1.f/(1.f+expf(-iv));
    float fg = 1.f/(1.f+expf(-fv));
    float gt = tanhf(gv);
    float og = 1.f/(1.f+expf(-ov));
    float cn = fg*cws[b*1024+J] + ig*gt;
    cws[b*1024+J] = cn;
    hnew[b*1024+J] = og*tanhf(cn);
  }
}

// P4: d1 + actor (sequential part)
__global__ __launch_bounds__(256) void p4_d1_actor(
  const u16* __restrict__ dseq, const float* __restrict__ dpre, float* __restrict__ dout,
  const float* __restrict__ hnew, const float* __restrict__ wgt, const float* __restrict__ ecur, int t)
{
  __shared__ u16 sA[8*2184];
  int tid = threadIdx.x;
  stage_sin(sA, hnew, wgt, ecur, tid);
  __syncthreads();
  int lane = tid & 63;
  int R = blockIdx.x*64 + (tid>>6)*16 + (lane & 15);
  const u16* bp = dseq + (size_t)R*2176 + ((lane>>4)*8);
  int aoff = (lane&7)*2184 + ((lane>>4)*8);
  f32x4 acc = {0,0,0,0};
  #pragma unroll 8
  for (int kk=0;kk<68;kk++){
    bf16x8 a = *(const bf16x8*)(&sA[aoff + kk*32]);
    bf16x8 b = *(const bf16x8*)(bp + kk*32);
    acc = __builtin_amdgcn_mfma_f32_16x16x32_bf16(a, b, acc, 0,0,0);
  }
  #pragma unroll
  for (int r=0;r<4;r++){
    int m = (lane>>4)*4 + r;
    if (m < 8){
      size_t row = (size_t)(m*24+t)*3264;
      dout[row + R] = acc[r] + dpre[row + R];
    }
  }
}

// ---------------------------------------------------------------- mask decode

__global__ __launch_bounds__(256) void k_m0up(const float* __restrict__ d1a_out, float* __restrict__ m0up, int btbase){
  int cb = blockIdx.x;
  int idx = blockIdx.y*256 + threadIdx.x;   // < 12544
  int i = idx / 196; int rest = idx - i*196; int y = rest/14, x = rest - y*14;
  float v = d1a_out[(size_t)(btbase+cb)*3264 + i*49 + (y>>1)*7 + (x>>1)];
  m0up[(size_t)cb*12544 + idx] = fmaxf(v, 0.f);
}

DEV void stage_tile(u16* sAt, int ldk, int Ktot, int Kreal, const float* in_bt, int H, int p0, int tid){
  int m = tid & 15;
  int p = p0 + m;
  int u = p / H, v = p - u*H;
  bool pv = p < H*H;
  for (int k = tid>>4; k < Ktot; k += 16){
    float val = 0.f;
    if (k < Kreal && pv){
      int i = k/9; int dd = k - i*9; int dy = dd/3, dx = dd - dy*3;
      int uy = u + dy - 1, vx = v + dx - 1;
      if (uy >= 0 && uy < H && vx >= 0 && vx < H) val = in_bt[((size_t)i*H + uy)*H + vx];
    }
    sAt[m*ldk + k] = f2b(val);
  }
}

// deconv3 (64->32, in-grid 14) with up2-on-write to m1up [32][56][56]
// flattened: one 16-position tile per block (mt = blockIdx.z), grid (C, 2, 13)
__global__ __launch_bounds__(256) void md3_deconv(const float* __restrict__ m0up, float* __restrict__ m1up,
  const u16* __restrict__ Wt3, const float* __restrict__ b3, const float* __restrict__ g3, const float* __restrict__ bb3)
{
  __shared__ u16 sAt[16*584];
  int tid = threadIdx.x, lane = tid&63, w = tid>>6;
  int cb = blockIdx.x;
  const float* in_bt = m0up + (size_t)cb*12544;
  float* out_bt = m1up + (size_t)cb*32*3136;
  int nt = blockIdx.y*4 + w;
  bf16x8 wc[18];
  #pragma unroll
  for (int ks=0;ks<18;ks++) wc[ks] = *(const bf16x8*)(Wt3 + (size_t)(nt*16 + (lane&15))*576 + ks*32 + (lane>>4)*8);
  int cls = nt>>1; int o = (nt&1)*16 + (lane&15);
  int py = cls>>1, px = cls&1;
  float cbv = b3[o], gv = g3[o], bbv = bb3[o];
  int mt = blockIdx.z;
  stage_tile(sAt, 584, 576, 576, in_bt, 14, mt*16, tid);
  __syncthreads();
  f32x4 acc = {0,0,0,0};
  #pragma unroll
  for (int ks=0;ks<18;ks++){
    bf16x8 a = *(const bf16x8*)(&sAt[(lane&15)*584 + ks*32 + (lane>>4)*8]);
    acc = __builtin_amdgcn_mfma_f32_16x16x32_bf16(a, wc[ks], acc, 0,0,0);
  }
  #pragma unroll
  for (int r=0;r<4;r++){
    int p = mt*16 + (lane>>4)*4 + r;
    if (p < 196){
      int u = p/14, v = p - (p/14)*14;
      float vv = fmaxf((acc[r] + cbv)*BN_INV*gv + bbv, 0.f);
      float* ob = out_bt + ((size_t)o*56 + 2*(2*u+py))*56 + 2*(2*v+px);
      ob[0]=vv; ob[1]=vv; ob[56]=vv; ob[57]=vv;
    }
  }
}

// deconv2 (32->16, in-grid 56) -> m2 [16][112][112]
// flattened: one 16-position tile per block (mt = blockIdx.y), grid (C, 196)
__global__ __launch_bounds__(256) void md2_deconv(const float* __restrict__ m1up, float* __restrict__ m2,
  const u16* __restrict__ Wt2, const float* __restrict__ b2, const float* __restrict__ g2, const float* __restrict__ bb2)
{
  __shared__ u16 sAt[16*296];
  int tid = threadIdx.x, lane = tid&63, w = tid>>6;
  int cb = blockIdx.x;
  const float* in_bt = m1up + (size_t)cb*32*3136;
  float* out_bt = m2 + (size_t)cb*16*12544;
  int nt = w;
  bf16x8 wc[9];
  #pragma unroll
  for (int ks=0;ks<9;ks++) wc[ks] = *(const bf16x8*)(Wt2 + (size_t)(nt*16 + (lane&15))*288 + ks*32 + (lane>>4)*8);
  int cls = nt; int o = lane&15;
  int py = cls>>1, px = cls&1;
  float cbv = b2[o], gv = g2[o], bbv = bb2[o];
  int mt = blockIdx.y;
  stage_tile(sAt, 296, 288, 288, in_bt, 56, mt*16, tid);
  __syncthreads();
  f32x4 acc = {0,0,0,0};
  #pragma unroll
  for (int ks=0;ks<9;ks++){
    bf16x8 a = *(const bf16x8*)(&sAt[(lane&15)*296 + ks*32 + (lane>>4)*8]);
    acc = __builtin_amdgcn_mfma_f32_16x16x32_bf16(a, wc[ks], acc, 0,0,0);
  }
  #pragma unroll
  for (int r=0;r<4;r++){
    int p = mt*16 + (lane>>4)*4 + r;
    if (p < 3136){
      int u = p/56, v = p - u*56;
      float vv = fmaxf((acc[r] + cbv)*BN_INV*gv + bbv, 0.f);
      out_bt[((size_t)o*112 + (2*u+py))*112 + (2*v+px)] = vv;
    }
  }
}

// deconv1 (16->1, in-grid 112) -> m3 [224][224], direct fp32 VALU.
// Each thread computes a 4-wide output quad out[oy][ox0..ox0+3].
// ConvT(k=4,s=2,p=1): out[oy][ox] = b + sum_i sum_taps in[i][iy][ix]*w[i][ky][kx],
// ky parity = !(oy&1): taps (kyA,iyA=(oy+1)>>1) and (kyA+2,iyA-1); same in x.
__global__ __launch_bounds__(256) void md1_direct(const float* __restrict__ m2, float* __restrict__ m3,
  const float* __restrict__ dw1, const float* __restrict__ b1)
{
  __shared__ float wl[256];               // dconv1_w: [i][ky][kx] = 16*4*4
  int tid = threadIdx.x;
  wl[tid] = dw1[tid];
  __syncthreads();
  int cb = blockIdx.x;
  const float* in_bt = m2 + (size_t)cb*16*12544;
  float* out_bt = m3 + (size_t)cb*50176;
  int idx = blockIdx.y*256 + tid;         // [0, 12544) : 224 rows x 56 quads
  int oy = idx/56, q = idx - oy*56;
  int ox0 = q*4;
  int iyA = (oy+1)>>1;  bool vA = iyA < 112;
  int iyB = iyA - 1;    bool vB = iyB >= 0;
  int kyA = (oy&1) ? 0 : 1;
  int kyB = kyA + 2;
  int xb = (ox0>>1) - 1;                  // load span xb..xb+3; xb+1,xb+2 always in [0,111]
  bool v0 = xb >= 0, v3 = (xb+3) < 112;
  int x0 = v0 ? xb : 0, x3 = v3 ? xb+3 : 111;
  float mA = vA ? 1.f : 0.f, mB = vB ? 1.f : 0.f;
  float mA0 = v0 ? mA : 0.f, mA3 = v3 ? mA : 0.f;
  float mB0 = v0 ? mB : 0.f, mB3 = v3 ? mB : 0.f;
  const float* rA = in_bt + (size_t)(vA ? iyA : 0)*112;
  const float* rB = in_bt + (size_t)(vB ? iyB : 0)*112;
  float acc0=0.f, acc1=0.f, acc2=0.f, acc3=0.f;
  #pragma unroll 4
  for (int i=0;i<16;i++){
    const float* cA = rA + i*12544;
    const float* cB = rB + i*12544;
    float a0 = cA[x0]*mA0, a1 = cA[xb+1]*mA, a2 = cA[xb+2]*mA, a3 = cA[x3]*mA3;
    float b0 = cB[x0]*mB0, b1v = cB[xb+1]*mB, b2 = cB[xb+2]*mB, b3 = cB[x3]*mB3;
    fl4 wA = *(const fl4*)(&wl[i*16 + kyA*4]);
    fl4 wB = *(const fl4*)(&wl[i*16 + kyB*4]);
    acc0 += a1*wA[1] + a0*wA[3] + b1v*wB[1] + b0*wB[3];
    acc1 += a2*wA[0] + a1*wA[2] + b2*wB[0] + b1v*wB[2];
    acc2 += a2*wA[1] + a1*wA[3] + b2*wB[1] + b1v*wB[3];
    acc3 += a3*wA[0] + a2*wA[2] + b3*wB[0] + b2*wB[2];
  }
  float bv = b1[0];
  fl4 o4 = {acc0+bv, acc1+bv, acc2+bv, acc3+bv};
  *(fl4*)(out_bt + (size_t)oy*224 + ox0) = o4;
}

__global__ __launch_bounds__(256) void k_resize(const float* __restrict__ m3, float* __restrict__ out_mask, int btbase){
  int cb = blockIdx.x;
  const float* in_bt = m3 + (size_t)cb*50176;
  int idx = blockIdx.y*256 + threadIdx.x;
  if (idx >= 90000) return;
  int oy = idx/300, ox = idx - oy*300;
  const float sc = 224.f/300.f;
  float sy = (oy+0.5f)*sc - 0.5f;
  float sx = (ox+0.5f)*sc - 0.5f;
  float fy = floorf(sy), fx = floorf(sx);
  float wy = sy-fy, wx = sx-fx;
  int y0 = (int)fy, x0 = (int)fx;
  int y0c = min(max(y0,0),223), y1c = min(max(y0+1,0),223);
  int x0c = min(max(x0,0),223), x1c = min(max(x0+1,0),223);
  float v00 = in_bt[y0c*224+x0c], v01 = in_bt[y0c*224+x1c];
  float v10 = in_bt[y1c*224+x0c], v11 = in_bt[y1c*224+x1c];
  float v = (1.f-wy)*((1.f-wx)*v00 + wx*v01) + wy*((1.f-wx)*v10 + wx*v11);
  out_mask[(size_t)(btbase+cb)*90000 + idx] = v;
}

// ---------------------------------------------------------------- host

extern "C" void kernel_launch(void* const* d_in, const int* in_sizes, int n_in,
                              void* d_out, int out_size, void* d_ws, size_t ws_size,
                              hipStream_t stream)
{
  const float* enc      = (const float*)d_in[0];
  const float* frames   = (const float*)d_in[1];
  const float* gcn      = (const float*)d_in[2];
  const float* h0       = (const float*)d_in[3];
  const float* c0       = (const float*)d_in[4];
  const float* conv1_w  = (const float*)d_in[5];
  const float* conv1_b  = (const float*)d_in[6];
  const float* bn1_g    = (const float*)d_in[7];
  const float* bn1_b    = (const float*)d_in[8];
  const float* conv2_w  = (const float*)d_in[9];
  const float* conv2_b  = (const float*)d_in[10];
  const float* bn2_g    = (const float*)d_in[11];
  const float* bn2_b    = (const float*)d_in[12];
  const float* fc_w     = (const float*)d_in[13];
  const float* fc_b     = (const float*)d_in[14];
  const float* hfc_w    = (const float*)d_in[15];
  const float* hfc_b    = (const float*)d_in[16];
  const float* w_ih     = (const float*)d_in[17];
  const float* w_hh     = (const float*)d_in[18];
  const float* b_ih     = (const float*)d_in[19];
  const float* b_hh     = (const float*)d_in[20];
  const float* go       = (const float*)d_in[21];
  const float* emb_w    = (const float*)d_in[22];
  const float* actor_w  = (const float*)d_in[23];
  const float* actor_b  = (const float*)d_in[24];
  const float* d1_w     = (const float*)d_in[25];
  const float* d1_b     = (const float*)d_in[26];
  const float* dconv3_w = (const float*)d_in[27];
  const float* dconv3_b = (const float*)d_in[28];
  const float* bnm2_g   = (const float*)d_in[29];
  const float* bnm2_b   = (const float*)d_in[30];
  const float* dconv2_w = (const float*)d_in[31];
  const float* dconv2_b = (const float*)d_in[32];
  const float* bnm1_g   = (const float*)d_in[33];
  const float* bnm1_b   = (const float*)d_in[34];
  const float* dconv1_w = (const float*)d_in[35];
  const float* dconv1_b = (const float*)d_in[36];
  (void)in_sizes; (void)n_in; (void)out_size;

  // ---- output layout (float element offsets)
  float* obase    = (float*)d_out;
  float* out_act  = obase;                // 196608
  float* out_mask = obase + 196608;       // 17280000 (69.12 MB — scratch arena until decode)
  float* out_attn = obase + 17476608;     // 27840
  float* out_h    = obase + 17504448;     // 8192
  float* out_c    = obase + 17512640;     // 8192

  // ---- big scratch arena = out_mask region, written only by the final decode phase
  char* ob = (char*)out_mask;
  size_t ooff = 0;
  auto oalloc = [&](size_t bytes)->char*{ char* p = ob + ooff; ooff = (ooff + bytes + 255) & ~(size_t)255; return p; };
  // live through the loop:
  u16*   wseq      = (u16*)  oalloc(4096ULL*2176*2);    // 17.8 MB
  u16*   dseq      = (u16*)  oalloc(3264ULL*2176*2);    // 14.2 MB
  float* encH      = (float*)oalloc(1160ULL*1024*4);    // 4.75 MB
  float* gates_pre = (float*)oalloc(192ULL*4096*4);     // 3.15 MB
  float* d1a_pre   = (float*)oalloc(192ULL*3264*4);     // 2.51 MB
  u16*   xin2      = (u16*)  oalloc(192ULL*3072*2);     // 1.18 MB (dead after pre-GEMMs)
  // transient conv-chain zone (dead before the loop starts):
  u16*   XT     = (u16*)oalloc(12288ULL*512*2);         // 12.6 MB
  u16*   Y1     = (u16*)oalloc(12288ULL*256*2);         // 6.3 MB
  u16*   Y2     = (u16*)oalloc(12288ULL*64*2);          // 1.6 MB
  u16*   vis_in = (u16*)oalloc(192ULL*3136*2);          // 1.2 MB
  u16*   vis    = (u16*)oalloc(192ULL*2500*2);          // 0.96 MB
  u16*   wchunk = XT;  // pre-GEMM weight chunk aliases XT (dead by then); 6.3MB <= 12.6MB
  // total ~66.3 MB <= 69.12 MB

  // ---- ws: small persistent state + d1a_out + hfcT/decode-chunk alias zone
  char* wsb = (char*)d_ws;
  size_t off = 0;
  auto alloc = [&](size_t bytes)->char*{ char* p = wsb + off; off = (off + bytes + 255) & ~(size_t)255; return p; };
  float* d1a_out   = (float*)alloc(192ULL*3264*4);      // 2.5 MB, read by decode
  u16*   embT      = (u16*)  alloc(128ULL*1024*2);
  float* eb        = (float*)alloc(1160ULL*4);
  u16*   Wt3       = (u16*)  alloc(128ULL*576*2);
  u16*   Wt2       = (u16*)  alloc(64ULL*288*2);
  u16*   Wt1       = (u16*)  alloc(16ULL*160*2);
  float* hb        = (float*)alloc(2ULL*8192*4);
  float* c_ws      = (float*)alloc(8192ULL*4);
  float* e_cur     = (float*)alloc(8ULL*128*4);
  float* weighted  = (float*)alloc(8192ULL*4);
  float* scores_raw= (float*)alloc(8ULL*145*4);
  float* cmv       = (float*)alloc(32ULL*4);
  int*   cmi       = (int*)  alloc(32ULL*4);
  float* bias_g    = (float*)alloc(4096ULL*4);
  float* bias_da   = (float*)alloc(3264ULL*4);
  size_t zbase = off;
  u16*   hfcT = (u16*)alloc(1024ULL*1024*2);            // dead after encH gemm

  // decode chunk buffers alias hfcT zone; per-bt = 1,455,104 B
  const int cands[10] = {48,24,16,12,8,6,4,3,2,1};
  int C = 1;
  for (int i=0;i<10;i++){
    size_t need = zbase + (size_t)cands[i]*1455104ULL + 65536;
    if (need <= ws_size){ C = cands[i]; break; }
  }
  size_t mo = zbase;
  auto malloc_ = [&](size_t bytes)->char*{ char* p = wsb + mo; mo = (mo + bytes + 255) & ~(size_t)255; return p; };
  float* m0up = (float*)malloc_((size_t)C*12544*4);
  float* m1up = (float*)malloc_((size_t)C*32*3136*4);
  float* m2b  = (float*)malloc_((size_t)C*16*12544*4);
  float* m3b  = (float*)malloc_((size_t)C*50176*4);

  // ---- upfront packs
  k_pack_frames<<<192, 256, 0, stream>>>(frames, XT);
  k_pack_wseq<<<4096, 256, 0, stream>>>(w_ih, w_hh, wseq);
  k_pack_dseq<<<3264, 256, 0, stream>>>(d1_w, actor_w, dseq);
  k_hfcT<<<4096, 256, 0, stream>>>(hfc_w, hfcT);
  k_misc<<<758, 256, 0, stream>>>(b_ih, b_hh, d1_b, actor_b, emb_w, h0, c0,
                                  dconv3_w, dconv2_w, dconv1_w,
                                  bias_g, bias_da, embT, hb, c_ws, Wt3, Wt2, Wt1);
  k_eb<<<290, 256, 0, stream>>>(enc, hfc_b, eb);

  // ---- upfront GEMMs (vis encoder chain + encH)
  gemm64<1,1><<<dim3(192,4), 256, 0, stream>>>(XT, 512, conv1_w, 512, Y1, 256, 12288, 256, 512, nullptr, conv1_b, bn1_g, bn1_b);
  gemm64<1,1><<<dim3(192,1), 256, 0, stream>>>(Y1, 256, conv2_w, 256, Y2, 64, 12288, 64, 256, nullptr, conv2_b, bn2_g, bn2_b);
  k_vis_in<<<192, 256, 0, stream>>>(Y2, vis_in);
  gemm64<1,0><<<dim3(3,40), 256, 0, stream>>>(vis_in, 3136, fc_w, 3136, vis, 2500, 192, 2500, 3136, fc_b, nullptr, nullptr, nullptr);
  k_xin<<<192, 256, 0, stream>>>(vis, gcn, xin2);
  gemm64<0,0><<<dim3(19,16), 256, 0, stream>>>(enc, 1024, hfcT, 1024, encH, 1024, 1160, 1024, 1024, nullptr, nullptr, nullptr, nullptr);

  // ---- pre-GEMMs for the (vis|gcn) columns, N-chunked (wchunk aliases XT, now dead)
  for (int c=0;c<4;c++){
    k_pack_wvg<<<1024, 256, 0, stream>>>(w_ih, wchunk, c*1024);
    gemm64<0,0><<<dim3(3,16), 256, 0, stream>>>(xin2, 3072, wchunk, 3072, gates_pre + c*1024, 4096,
                                                192, 1024, 3072, bias_g + c*1024, nullptr, nullptr, nullptr);
  }
  for (int c=0;c<3;c++){
    k_pack_dvg<<<1088, 256, 0, stream>>>(d1_w, actor_w, wchunk, c*1088);
    gemm64<0,0><<<dim3(3,17), 256, 0, stream>>>(xin2, 3072, wchunk, 3072, d1a_pre + c*1088, 3264,
                                                192, 1088, 3072, bias_da + c*1088, nullptr, nullptr, nullptr);
  }

  // ---- sequential loop
  for (int t=0; t<=24; t++){
    float* hcur = hb + (t&1)*8192;
    float* hnew = hb + ((t+1)&1)*8192;
    p1_scores_action<<<80, 256, 0, stream>>>(encH, eb, hcur, c_ws, scores_raw, d1a_out, embT,
                                             out_act, cmv, cmi, out_h, out_c, t);
    if (t == 24) break;
    p2_softmax_weighted<<<64, 256, 0, stream>>>(scores_raw, enc, weighted, e_cur, cmv, cmi, emb_w, go, out_attn, t);
    p3_gates_lstm<<<64, 256, 0, stream>>>(wseq, gates_pre, hcur, hnew, c_ws, weighted, e_cur, t);
    p4_d1_actor<<<51, 256, 0, stream>>>(dseq, d1a_pre, d1a_out, hnew, weighted, e_cur, t);
  }

  // ---- mask decode (192/C chunks of C bt) — overwrites the out-scratch arena, reads only d1a_out (ws)
  for (int btbase=0; btbase<192; btbase+=C){
    k_m0up<<<dim3(C,49), 256, 0, stream>>>(d1a_out, m0up, btbase);
    md3_deconv<<<dim3(C,2,13), 256, 0, stream>>>(m0up, m1up, Wt3, dconv3_b, bnm2_g, bnm2_b);
    md2_deconv<<<dim3(C,196), 256, 0, stream>>>(m1up, m2b, Wt2, dconv2_b, bnm1_g, bnm1_b);
    md1_direct<<<dim3(C,49), 256, 0, stream>>>(m2b, m3b, dconv1_w, dconv1_b);
    k_resize<<<dim3(C,352), 256, 0, stream>>>(m3b, out_mask, btbase);
  }
}

// Round 3
// 3286.109 us; speedup vs baseline: 1.8256x; 1.1687x over previous
//
#include <hip/hip_runtime.h>
#include <cstdint>
#include <cstddef>

#define DEV __device__ __forceinline__
typedef short bf16x8 __attribute__((ext_vector_type(8)));
typedef float fl4 __attribute__((ext_vector_type(4)));
typedef float f32x4 __attribute__((ext_vector_type(4)));
typedef unsigned short u16;

#define BN_INV 0.9999950000375f

DEV float b2f(u16 u){ return __uint_as_float(((unsigned)u)<<16); }
DEV u16 f2b(float f){ unsigned u = __float_as_uint(f); unsigned r = (u + 0x7FFFu + ((u>>16)&1u))>>16; return (u16)r; }

DEV bf16x8 load8(const u16* p){ return *(const bf16x8*)p; }
DEV bf16x8 load8(const float* p){
  fl4 a = *(const fl4*)p; fl4 b = *(const fl4*)(p+4);
  bf16x8 r;
  r[0]=(short)f2b(a[0]); r[1]=(short)f2b(a[1]); r[2]=(short)f2b(a[2]); r[3]=(short)f2b(a[3]);
  r[4]=(short)f2b(b[0]); r[5]=(short)f2b(b[1]); r[6]=(short)f2b(b[2]); r[7]=(short)f2b(b[3]);
  return r;
}

// ---------------------------------------------------------------- pack kernels

// frames [192][512][49] f32 -> XT [192*64][512] bf16 (rows p>=49 zero)
__global__ __launch_bounds__(256) void k_pack_frames(const float* __restrict__ fr, u16* __restrict__ XT){
  int bt = blockIdx.x, tid = threadIdx.x;
  for (int e=0;e<128;e++){
    int flat = e*256 + tid;           // < 32768
    int p = flat>>9, c = flat&511;
    u16 v = 0;
    if (p < 49) v = f2b(fr[((size_t)bt*512 + c)*49 + p]);
    XT[((size_t)bt*64 + p)*512 + c] = v;
  }
}

// wseq [4096][2176] bf16 = [w_hh | w_ih cols 2500:3652]
__global__ __launch_bounds__(256) void k_pack_wseq(const float* __restrict__ w_ih, const float* __restrict__ w_hh,
                                                   u16* __restrict__ wseq){
  int r = blockIdx.x, tid = threadIdx.x;
  const float* wr = w_ih + (size_t)r*4164;
  for (int j=tid;j<2176;j+=256){
    float v = (j < 1024) ? w_hh[(size_t)r*1024 + j] : wr[2500 + (j-1024)];
    wseq[(size_t)r*2176 + j] = f2b(v);
  }
}

// dseq [3264][2176] bf16 = [dw cols 0:1024 | dw cols 3524:4676]  (rows 0:3136 d1_w, then actor_w)
__global__ __launch_bounds__(256) void k_pack_dseq(const float* __restrict__ d1_w, const float* __restrict__ actor_w,
                                                   u16* __restrict__ dseq){
  int r = blockIdx.x, tid = threadIdx.x;
  const float* wr = (r < 3136) ? (d1_w + (size_t)r*5188) : (actor_w + (size_t)(r-3136)*5188);
  for (int j=tid;j<2176;j+=256){
    float v = (j < 1024) ? wr[j] : wr[3524 + (j-1024)];
    dseq[(size_t)r*2176 + j] = f2b(v);
  }
}

// wvg chunk [1024][3072] bf16 = [w_ih cols 0:2500 | w_ih cols 3652:4164 | 0]
__global__ __launch_bounds__(256) void k_pack_wvg(const float* __restrict__ w_ih, u16* __restrict__ wvg, int rbase){
  int r = rbase + blockIdx.x, tid = threadIdx.x;
  const float* wr = w_ih + (size_t)r*4164;
  u16* dst = wvg + (size_t)blockIdx.x*3072;
  for (int j=tid;j<3072;j+=256){
    float v = 0.f;
    if (j < 2500) v = wr[j];
    else if (j < 3012) v = wr[3652 + (j-2500)];
    dst[j] = f2b(v);
  }
}

// dvg chunk [1088][3072] bf16 = [dw cols 1024:3524 | dw cols 4676:5188 | 0]
__global__ __launch_bounds__(256) void k_pack_dvg(const float* __restrict__ d1_w, const float* __restrict__ actor_w,
                                                  u16* __restrict__ dvg, int rbase){
  int r = rbase + blockIdx.x, tid = threadIdx.x;
  const float* wr = (r < 3136) ? (d1_w + (size_t)r*5188) : (actor_w + (size_t)(r-3136)*5188);
  u16* dst = dvg + (size_t)blockIdx.x*3072;
  for (int j=tid;j<3072;j+=256){
    float v = 0.f;
    if (j < 2500) v = wr[1024 + j];
    else if (j < 3012) v = wr[4676 + (j-2500)];
    dst[j] = f2b(v);
  }
}

__global__ __launch_bounds__(256) void k_hfcT(const float* __restrict__ hfc_w, u16* __restrict__ hfcT){
  int idx = blockIdx.x*256 + threadIdx.x;   // 1M
  int k = idx>>10, o = idx&1023;
  hfcT[idx] = f2b(hfc_w[o*1024 + k]);
}

DEV u16 wt_map(const float* w, int n, int k, int CIN, int COUT){
  int o = n % COUT; int cls = n / COUT;
  if (cls >= 4) return 0;
  int py = cls>>1, px = cls&1;
  int i = k/9; int dd = k - i*9; int dy = dd/3, dx = dd - dy*3;
  if (i >= CIN) return 0;
  int ky = (py==0) ? (dy==0 ? 3 : (dy==1 ? 1 : -1)) : (dy==1 ? 2 : (dy==2 ? 0 : -1));
  int kx = (px==0) ? (dx==0 ? 3 : (dx==1 ? 1 : -1)) : (dx==1 ? 2 : (dx==2 ? 0 : -1));
  if (ky < 0 || kx < 0) return 0;
  return f2b(w[((i*COUT + o)*4 + ky)*4 + kx]);
}

__global__ __launch_bounds__(256) void k_misc(
  const float* b_ih, const float* b_hh, const float* d1_b, const float* actor_b,
  const float* emb_w, const float* h0, const float* c0,
  const float* dw3, const float* dw2, const float* dw1,
  float* bias_g, float* bias_da, u16* embT, float* hb0, float* cws,
  u16* Wt3, u16* Wt2, u16* Wt1)
{
  int blk = blockIdx.x, tid = threadIdx.x;
  if (blk < 16){ int i = blk*256+tid; if (i<4096) bias_g[i] = b_ih[i] + b_hh[i]; }
  else if (blk < 29){ int i = (blk-16)*256+tid; if (i<3264) bias_da[i] = (i<3136)? d1_b[i] : actor_b[i-3136]; }
  else if (blk < 541){ int i = (blk-29)*256+tid; int j = i>>10, v = i&1023; embT[i] = f2b(emb_w[v*128 + j]); }
  else if (blk < 573){ int i = (blk-541)*256+tid; if (i<8192){ hb0[i] = h0[i]; cws[i] = c0[i]; } }
  else if (blk < 574){ for (int i=tid;i<2560;i+=256){ int n=i/160, k=i-n*160; Wt1[i] = wt_map(dw1,n,k,16,1); } }
  else if (blk < 590){ for (int i=(blk-574)*256+tid; i<18432; i+=16*256){ int n=i/288, k=i-n*288; Wt2[i] = wt_map(dw2,n,k,32,16); } }
  else { for (int i=(blk-590)*256+tid; i<73728; i+=168*256){ int n=i/576, k=i-n*576; Wt3[i] = wt_map(dw3,n,k,64,32); } }
}

__global__ __launch_bounds__(256) void k_eb(const float* __restrict__ enc, const float* __restrict__ hfc_b, float* __restrict__ eb){
  int li = blockIdx.x*4 + (threadIdx.x>>6);
  int lane = threadIdx.x & 63;
  if (li >= 1160) return;
  const float* ep = enc + (size_t)li*1024;
  float a = 0.f;
  for (int k=lane;k<1024;k+=64) a += ep[k]*hfc_b[k];
  #pragma unroll
  for (int off=32; off; off>>=1) a += __shfl_xor(a, off);
  if (lane == 0) eb[li] = a;
}

// Y2 [192*64][64] bf16 -> vis_in [192][3136] bf16 (c*49+p ordering)
__global__ __launch_bounds__(256) void k_vis_in(const u16* __restrict__ Y2, u16* __restrict__ vis_in){
  int bt = blockIdx.x, tid = threadIdx.x;
  for (int f=tid; f<3136; f+=256){
    int c = f/49, p = f - c*49;
    vis_in[(size_t)bt*3136 + f] = Y2[((size_t)bt*64 + p)*64 + c];
  }
}

// xin2 [192][3072] bf16 = [vis 2500 | gcn 512 | 0]
__global__ __launch_bounds__(256) void k_xin(const u16* __restrict__ vis, const float* __restrict__ gcn, u16* __restrict__ xin2){
  int bt = blockIdx.x, tid = threadIdx.x, b = bt/24;
  for (int j=tid;j<3072;j+=256){
    u16 v = 0;
    if (j < 2500) v = vis[(size_t)bt*2500 + j];
    else if (j < 3012) v = f2b(gcn[b*512 + (j-2500)]);
    xin2[(size_t)bt*3072 + j] = v;
  }
}

// ---------------------------------------------------------------- generic MFMA GEMM (C[M,N] = A[M,K] @ B[N,K]^T)
// 64x64-tile version (used where M is large); bitwise reference order: k-slices of 32, increasing.
template<int OUTB, int ACT, typename TA, typename TB>
__global__ __launch_bounds__(256) void gemm64(
  const TA* __restrict__ A, int lda, const TB* __restrict__ Bm, int ldb,
  void* __restrict__ Cv, int ldc, int M, int N, int K,
  const float* __restrict__ bias, const float* __restrict__ cb, const float* __restrict__ gg, const float* __restrict__ bb)
{
  __shared__ u16 sA[64*72];
  __shared__ u16 sB[64*72];
  int tid = threadIdx.x, lane = tid & 63, w = tid >> 6;
  int wm = w & 1, wn = w >> 1;
  int m0 = blockIdx.x*64, n0 = blockIdx.y*64;
  f32x4 acc[2][2];
  #pragma unroll
  for (int a=0;a<2;a++)
    #pragma unroll
    for (int b=0;b<2;b++){ acc[a][b][0]=0;acc[a][b][1]=0;acc[a][b][2]=0;acc[a][b][3]=0; }

  for (int k0=0;k0<K;k0+=64){
    #pragma unroll
    for (int j=0;j<2;j++){
      int c = tid + 256*j; int row = c>>3; int col = (c&7)*8;
      bf16x8 va = {0,0,0,0,0,0,0,0};
      int gm = m0 + row;
      if (gm < M) va = load8(A + (size_t)gm*lda + k0 + col);
      *(bf16x8*)(&sA[row*72 + col]) = va;
      bf16x8 vb = {0,0,0,0,0,0,0,0};
      int gn = n0 + row;
      if (gn < N) vb = load8(Bm + (size_t)gn*ldb + k0 + col);
      *(bf16x8*)(&sB[row*72 + col]) = vb;
    }
    __syncthreads();
    #pragma unroll
    for (int kk=0;kk<2;kk++){
      bf16x8 af[2], bfv[2];
      #pragma unroll
      for (int tm=0;tm<2;tm++) af[tm]  = *(const bf16x8*)(&sA[(wm*32+tm*16+(lane&15))*72 + kk*32 + (lane>>4)*8]);
      #pragma unroll
      for (int tn=0;tn<2;tn++) bfv[tn] = *(const bf16x8*)(&sB[(wn*32+tn*16+(lane&15))*72 + kk*32 + (lane>>4)*8]);
      #pragma unroll
      for (int tm=0;tm<2;tm++)
        #pragma unroll
        for (int tn=0;tn<2;tn++)
          acc[tm][tn] = __builtin_amdgcn_mfma_f32_16x16x32_bf16(af[tm], bfv[tn], acc[tm][tn], 0,0,0);
    }
    __syncthreads();
  }
  int ml = (lane>>4)*4, nl = lane&15;
  #pragma unroll
  for (int tm=0;tm<2;tm++)
    #pragma unroll
    for (int tn=0;tn<2;tn++)
      #pragma unroll
      for (int r=0;r<4;r++){
        int gm = m0 + wm*32 + tm*16 + ml + r;
        int gn = n0 + wn*32 + tn*16 + nl;
        if (gm < M && gn < N){
          float v = acc[tm][tn][r];
          if (ACT == 0){ if (bias) v += bias[gn]; }
          else { v = (v + cb[gn])*BN_INV*gg[gn] + bb[gn]; v = fmaxf(v, 0.f); }
          if (OUTB) ((u16*)Cv)[(size_t)gm*ldc + gn] = f2b(v);
          else      ((float*)Cv)[(size_t)gm*ldc + gn] = v;
        }
      }
}

// 16x16-tile 1-wave GEMM: bitwise-identical per-output accumulation chain
// (same increasing k-slice order, same f2b operand conversion) as gemm64,
// but one wave per block -> grid = (M/16)x(N/16) blocks for latency hiding.
template<int OUTB, typename TA, typename TB>
__global__ __launch_bounds__(64) void gemm16(
  const TA* __restrict__ A, int lda, const TB* __restrict__ Bm, int ldb,
  void* __restrict__ Cv, int ldc, int M, int N, int K, const float* __restrict__ bias)
{
  int lane = threadIdx.x;
  int m0 = blockIdx.x*16, n0 = blockIdx.y*16;
  int gm = m0 + (lane&15); if (gm > M-1) gm = M-1;   // clamp: rows >=M never stored
  int gn = n0 + (lane&15); if (gn > N-1) gn = N-1;   // clamp: cols >=N never stored
  const TA* ap = A  + (size_t)gm*lda + ((lane>>4)*8);
  const TB* bp = Bm + (size_t)gn*ldb + ((lane>>4)*8);
  f32x4 acc = {0,0,0,0};
  #pragma unroll 4
  for (int ks=0; ks<K; ks+=32){
    bf16x8 a = load8(ap + ks);
    bf16x8 b = load8(bp + ks);
    acc = __builtin_amdgcn_mfma_f32_16x16x32_bf16(a, b, acc, 0,0,0);
  }
  int nn = n0 + (lane&15);
  if (nn >= N) return;
  #pragma unroll
  for (int r=0;r<4;r++){
    int mm = m0 + (lane>>4)*4 + r;
    if (mm < M){
      float v = acc[r];
      if (bias) v += bias[nn];
      if (OUTB) ((u16*)Cv)[(size_t)mm*ldc + nn] = f2b(v);
      else      ((float*)Cv)[(size_t)mm*ldc + nn] = v;
    }
  }
}

// ---------------------------------------------------------------- per-step kernels

// P1: scores (blocks 0-39) + action/argmax of t-1 (40-71) + h-pack / h,c output (72-79)
__global__ __launch_bounds__(256) void p1_scores_action(
  const float* __restrict__ encH, const float* __restrict__ eb,
  const float* __restrict__ hcur, const float* __restrict__ cws,
  float* __restrict__ scores, const float* __restrict__ d1a_out,
  const u16* __restrict__ embT, float* __restrict__ out_act,
  float* __restrict__ cmv, int* __restrict__ cmi,
  float* __restrict__ out_h, float* __restrict__ out_c,
  u16* __restrict__ xb1, int t)
{
  __shared__ float shf[1024];
  __shared__ int shi[256];
  int blk = blockIdx.x, tid = threadIdx.x;
  if (blk < 40){
    if (t == 24) return;
    int b = blk/5, lc = blk - b*5;
    #pragma unroll
    for (int e=0;e<4;e++) shf[tid + 256*e] = hcur[b*1024 + tid + 256*e];
    __syncthreads();
    int w = tid>>6, lane = tid&63;
    for (int i=w;i<29;i+=4){
      int l = lc*29 + i;
      const float* ep = encH + (size_t)(b*145+l)*1024;
      float a = 0.f;
      for (int k=lane;k<1024;k+=64) a += ep[k]*shf[k];
      #pragma unroll
      for (int off=32; off; off>>=1) a += __shfl_xor(a, off);
      if (lane == 0) scores[b*145+l] = a + eb[b*145+l];
    }
  } else if (blk < 72){
    if (t == 0) return;
    int idx = blk-40; int b = idx>>2, vc = idx&3;
    if (tid < 128) shf[tid] = d1a_out[(size_t)(b*24 + t-1)*3264 + 3136 + tid];
    __syncthreads();
    int v = vc*256 + tid;
    float a = 0.f;
    for (int j=0;j<128;j++) a += shf[j]*b2f(embT[j*1024 + v]);
    out_act[(size_t)(b*24 + t-1)*1024 + v] = a;
    shf[256+tid] = a; shi[tid] = v;
    __syncthreads();
    for (int s=128; s; s>>=1){
      if (tid < s){
        float o = shf[256+tid+s]; int oi = shi[tid+s];
        float c = shf[256+tid];   int ci = shi[tid];
        if (o > c || (o == c && oi < ci)){ shf[256+tid] = o; shi[tid] = oi; }
      }
      __syncthreads();
    }
    if (tid == 0){ cmv[b*4+vc] = shf[256]; cmi[b*4+vc] = shi[0]; }
  } else {
    int b = blk-72;
    if (t == 24){
      #pragma unroll
      for (int e=0;e<4;e++){
        int k = tid + 256*e;
        out_h[b*1024+k] = hcur[b*1024+k];
        out_c[b*1024+k] = cws[b*1024+k];
      }
    } else {
      #pragma unroll
      for (int e=0;e<4;e++){
        int k = tid + 256*e;
        xb1[b*2176 + k] = f2b(hcur[b*1024+k]);
      }
    }
  }
}

// P2: softmax + weighted + attn-out + e selection; also packs wgt/e slices into xb1/xb2
__global__ __launch_bounds__(256) void p2_softmax_weighted(
  const float* __restrict__ scores, const float* __restrict__ enc,
  float* __restrict__ wgt, float* __restrict__ ecur,
  const float* __restrict__ cmv, const int* __restrict__ cmi,
  const float* __restrict__ emb_w, const float* __restrict__ go,
  float* __restrict__ out_attn, u16* __restrict__ xb1, u16* __restrict__ xb2, int t)
{
  int b = blockIdx.x >> 3, dc = blockIdx.x & 7, tid = threadIdx.x;
  __shared__ float s[145];
  __shared__ float mxs, invs;
  if (tid < 145) s[tid] = scores[b*145+tid];
  __syncthreads();
  if (tid < 64){
    float m = -1e30f;
    for (int i=tid;i<145;i+=64) m = fmaxf(m, s[i]);
    #pragma unroll
    for (int off=32; off; off>>=1) m = fmaxf(m, __shfl_xor(m, off));
    if (tid == 0) mxs = m;
  }
  __syncthreads();
  if (tid < 145) s[tid] = expf(s[tid]-mxs);
  __syncthreads();
  if (tid < 64){
    float sm = 0.f;
    for (int i=tid;i<145;i+=64) sm += s[i];
    #pragma unroll
    for (int off=32; off; off>>=1) sm += __shfl_xor(sm, off);
    if (tid == 0) invs = 1.f/sm;
  }
  __syncthreads();
  float inv = invs;
  if (tid < 128){
    int d = dc*128 + tid;
    float a = 0.f;
    for (int l=0;l<145;l++) a += s[l]*enc[(size_t)(b*145+l)*1024 + d];
    float wv = a*inv;
    wgt[b*1024+d] = wv;
    u16 wb = f2b(wv);
    xb1[b*2176 + 1024 + d] = wb;
    xb2[b*2176 + 1024 + d] = wb;
  } else {
    int i = tid-128;
    if (dc == 0){
      if (i < 145) out_attn[(size_t)(b*24+t)*145 + i] = s[i]*inv;
      int l2 = i + 128;
      if (l2 < 145) out_attn[(size_t)(b*24+t)*145 + l2] = s[l2]*inv;
    } else if (dc == 1){
      float ev;
      if (t == 0) ev = go[i];
      else {
        float bv = cmv[b*4]; int bi = cmi[b*4];
        #pragma unroll
        for (int c=1;c<4;c++){
          float v2 = cmv[b*4+c]; int i2 = cmi[b*4+c];
          if (v2 > bv || (v2 == bv && i2 < bi)){ bv = v2; bi = i2; }
        }
        ev = emb_w[bi*128 + i];
      }
      ecur[b*128+i] = ev;
      u16 eb16 = f2b(ev);
      xb1[b*2176 + 2048 + i] = eb16;
      xb2[b*2176 + 2048 + i] = eb16;
    }
  }
}

// P3m: gates GEMM, one wave per 16 output cols; bitwise-identical 68-MFMA chain.
// grid 256 x 64 threads. gates4[b][n] for b<8, n<4096.
__global__ __launch_bounds__(64) void p3m(
  const u16* __restrict__ wseq, const u16* __restrict__ xb, float* __restrict__ gates4)
{
  int lane = threadIdx.x;
  int n = blockIdx.x*16 + (lane & 15);
  const u16* bp = wseq + (size_t)n*2176 + ((lane>>4)*8);
  const u16* ap = xb + (lane&7)*2176 + ((lane>>4)*8);
  f32x4 acc = {0,0,0,0};
  #pragma unroll 4
  for (int kk=0;kk<68;kk++){
    bf16x8 a = *(const bf16x8*)(ap + kk*32);
    bf16x8 b = *(const bf16x8*)(bp + kk*32);
    acc = __builtin_amdgcn_mfma_f32_16x16x32_bf16(a, b, acc, 0,0,0);
  }
  #pragma unroll
  for (int r=0;r<4;r++){
    int m = (lane>>4)*4 + r;
    if (m < 8) gates4[(size_t)m*4096 + n] = acc[r];
  }
}

// P3l: LSTM elementwise (same add order as round-1 fused epilogue); packs hnew into xb2.
__global__ __launch_bounds__(256) void p3l(
  const float* __restrict__ gates4, const float* __restrict__ gpre,
  float* __restrict__ hnew, float* __restrict__ cws, u16* __restrict__ xb2, int t)
{
  int idx = blockIdx.x*256 + threadIdx.x;   // 8192
  int b = idx>>10, J = idx&1023;
  const float* gp = gpre + (size_t)(b*24+t)*4096;
  const float* gb = gates4 + (size_t)b*4096;
  float iv = gb[J]      + gp[J];
  float fv = gb[1024+J] + gp[1024+J];
  float gv = gb[2048+J] + gp[2048+J];
  float ov = gb[3072+J] + gp[3072+J];
  float ig = 1.f/(1.f+expf(-iv));
  float fg = 1.f/(1.f+expf(-fv));
  float gt = tanhf(gv);
  float og = 1.f/(1.f+expf(-ov));
  float cn = fg*cws[idx] + ig*gt;
  cws[idx] = cn;
  float hv = og*tanhf(cn);
  hnew[idx] = hv;
  xb2[b*2176 + J] = f2b(hv);
}

// P4m: d1+actor GEMM, one wave per 16 output cols; bitwise-identical chain. grid 204 x 64.
__global__ __launch_bounds__(64) void p4m(
  const u16* __restrict__ dseq, const u16* __restrict__ xb2,
  const float* __restrict__ dpre, float* __restrict__ dout, int t)
{
  int lane = threadIdx.x;
  int R = blockIdx.x*16 + (lane & 15);
  const u16* bp = dseq + (size_t)R*2176 + ((lane>>4)*8);
  const u16* ap = xb2 + (lane&7)*2176 + ((lane>>4)*8);
  f32x4 acc = {0,0,0,0};
  #pragma unroll 4
  for (int kk=0;kk<68;kk++){
    bf16x8 a = *(const bf16x8*)(ap + kk*32);
    bf16x8 b = *(const bf16x8*)(bp + kk*32);
    acc = __builtin_amdgcn_mfma_f32_16x16x32_bf16(a, b, acc, 0,0,0);
  }
  #pragma unroll
  for (int r=0;r<4;r++){
    int m = (lane>>4)*4 + r;
    if (m < 8){
      size_t row = (size_t)(m*24+t)*3264;
      dout[row + R] = acc[r] + dpre[row + R];
    }
  }
}

// ---------------------------------------------------------------- mask decode

__global__ __launch_bounds__(256) void k_m0up(const float* __restrict__ d1a_out, float* __restrict__ m0up, int btbase){
  int cb = blockIdx.x;
  int idx = blockIdx.y*256 + threadIdx.x;   // < 12544
  int i = idx / 196; int rest = idx - i*196; int y = rest/14, x = rest - y*14;
  float v = d1a_out[(size_t)(btbase+cb)*3264 + i*49 + (y>>1)*7 + (x>>1)];
  m0up[(size_t)cb*12544 + idx] = fmaxf(v, 0.f);
}

DEV void stage_tile(u16* sAt, int ldk, int Ktot, int Kreal, const float* in_bt, int H, int p0, int tid){
  int m = tid & 15;
  int p = p0 + m;
  int u = p / H, v = p - u*H;
  bool pv = p < H*H;
  for (int k = tid>>4; k < Ktot; k += 16){
    float val = 0.f;
    if (k < Kreal && pv){
      int i = k/9; int dd = k - i*9; int dy = dd/3, dx = dd - dy*3;
      int uy = u + dy - 1, vx = v + dx - 1;
      if (uy >= 0 && uy < H && vx >= 0 && vx < H) val = in_bt[((size_t)i*H + uy)*H + vx];
    }
    sAt[m*ldk + k] = f2b(val);
  }
}

// deconv3 (64->32, in-grid 14) with up2-on-write to m1up [32][56][56]; grid (C, 2, 13)
__global__ __launch_bounds__(256) void md3_deconv(const float* __restrict__ m0up, float* __restrict__ m1up,
  const u16* __restrict__ Wt3, const float* __restrict__ b3, const float* __restrict__ g3, const float* __restrict__ bb3)
{
  __shared__ u16 sAt[16*584];
  int tid = threadIdx.x, lane = tid&63, w = tid>>6;
  int cb = blockIdx.x;
  const float* in_bt = m0up + (size_t)cb*12544;
  float* out_bt = m1up + (size_t)cb*32*3136;
  int nt = blockIdx.y*4 + w;
  bf16x8 wc[18];
  #pragma unroll
  for (int ks=0;ks<18;ks++) wc[ks] = *(const bf16x8*)(Wt3 + (size_t)(nt*16 + (lane&15))*576 + ks*32 + (lane>>4)*8);
  int cls = nt>>1; int o = (nt&1)*16 + (lane&15);
  int py = cls>>1, px = cls&1;
  float cbv = b3[o], gv = g3[o], bbv = bb3[o];
  int mt = blockIdx.z;
  stage_tile(sAt, 584, 576, 576, in_bt, 14, mt*16, tid);
  __syncthreads();
  f32x4 acc = {0,0,0,0};
  #pragma unroll
  for (int ks=0;ks<18;ks++){
    bf16x8 a = *(const bf16x8*)(&sAt[(lane&15)*584 + ks*32 + (lane>>4)*8]);
    acc = __builtin_amdgcn_mfma_f32_16x16x32_bf16(a, wc[ks], acc, 0,0,0);
  }
  #pragma unroll
  for (int r=0;r<4;r++){
    int p = mt*16 + (lane>>4)*4 + r;
    if (p < 196){
      int u = p/14, v = p - (p/14)*14;
      float vv = fmaxf((acc[r] + cbv)*BN_INV*gv + bbv, 0.f);
      float* ob = out_bt + ((size_t)o*56 + 2*(2*u+py))*56 + 2*(2*v+px);
      ob[0]=vv; ob[1]=vv; ob[56]=vv; ob[57]=vv;
    }
  }
}

// deconv2 (32->16, in-grid 56) -> m2 [16][112][112]; grid (C, 196)
__global__ __launch_bounds__(256) void md2_deconv(const float* __restrict__ m1up, float* __restrict__ m2,
  const u16* __restrict__ Wt2, const float* __restrict__ b2, const float* __restrict__ g2, const float* __restrict__ bb2)
{
  __shared__ u16 sAt[16*296];
  int tid = threadIdx.x, lane = tid&63, w = tid>>6;
  int cb = blockIdx.x;
  const float* in_bt = m1up + (size_t)cb*32*3136;
  float* out_bt = m2 + (size_t)cb*16*12544;
  int nt = w;
  bf16x8 wc[9];
  #pragma unroll
  for (int ks=0;ks<9;ks++) wc[ks] = *(const bf16x8*)(Wt2 + (size_t)(nt*16 + (lane&15))*288 + ks*32 + (lane>>4)*8);
  int cls = nt; int o = lane&15;
  int py = cls>>1, px = cls&1;
  float cbv = b2[o], gv = g2[o], bbv = bb2[o];
  int mt = blockIdx.y;
  stage_tile(sAt, 296, 288, 288, in_bt, 56, mt*16, tid);
  __syncthreads();
  f32x4 acc = {0,0,0,0};
  #pragma unroll
  for (int ks=0;ks<9;ks++){
    bf16x8 a = *(const bf16x8*)(&sAt[(lane&15)*296 + ks*32 + (lane>>4)*8]);
    acc = __builtin_amdgcn_mfma_f32_16x16x32_bf16(a, wc[ks], acc, 0,0,0);
  }
  #pragma unroll
  for (int r=0;r<4;r++){
    int p = mt*16 + (lane>>4)*4 + r;
    if (p < 3136){
      int u = p/56, v = p - u*56;
      float vv = fmaxf((acc[r] + cbv)*BN_INV*gv + bbv, 0.f);
      out_bt[((size_t)o*112 + (2*u+py))*112 + (2*v+px)] = vv;
    }
  }
}

// deconv1 (16->1, in-grid 112) -> m3 [224][224], direct fp32 VALU.
__global__ __launch_bounds__(256) void md1_direct(const float* __restrict__ m2, float* __restrict__ m3,
  const float* __restrict__ dw1, const float* __restrict__ b1)
{
  __shared__ float wl[256];               // dconv1_w: [i][ky][kx] = 16*4*4
  int tid = threadIdx.x;
  wl[tid] = dw1[tid];
  __syncthreads();
  int cb = blockIdx.x;
  const float* in_bt = m2 + (size_t)cb*16*12544;
  float* out_bt = m3 + (size_t)cb*50176;
  int idx = blockIdx.y*256 + tid;         // [0, 12544) : 224 rows x 56 quads
  int oy = idx/56, q = idx - oy*56;
  int ox0 = q*4;
  int iyA = (oy+1)>>1;  bool vA = iyA < 112;
  int iyB = iyA - 1;    bool vB = iyB >= 0;
  int kyA = (oy&1) ? 0 : 1;
  int kyB = kyA + 2;
  int xb = (ox0>>1) - 1;
  bool v0 = xb >= 0, v3 = (xb+3) < 112;
  int x0 = v0 ? xb : 0, x3 = v3 ? xb+3 : 111;
  float mA = vA ? 1.f : 0.f, mB = vB ? 1.f : 0.f;
  float mA0 = v0 ? mA : 0.f, mA3 = v3 ? mA : 0.f;
  float mB0 = v0 ? mB : 0.f, mB3 = v3 ? mB : 0.f;
  const float* rA = in_bt + (size_t)(vA ? iyA : 0)*112;
  const float* rB = in_bt + (size_t)(vB ? iyB : 0)*112;
  float acc0=0.f, acc1=0.f, acc2=0.f, acc3=0.f;
  #pragma unroll 4
  for (int i=0;i<16;i++){
    const float* cA = rA + i*12544;
    const float* cB = rB + i*12544;
    float a0 = cA[x0]*mA0, a1 = cA[xb+1]*mA, a2 = cA[xb+2]*mA, a3 = cA[x3]*mA3;
    float b0 = cB[x0]*mB0, b1v = cB[xb+1]*mB, b2 = cB[xb+2]*mB, b3 = cB[x3]*mB3;
    fl4 wA = *(const fl4*)(&wl[i*16 + kyA*4]);
    fl4 wB = *(const fl4*)(&wl[i*16 + kyB*4]);
    acc0 += a1*wA[1] + a0*wA[3] + b1v*wB[1] + b0*wB[3];
    acc1 += a2*wA[0] + a1*wA[2] + b2*wB[0] + b1v*wB[2];
    acc2 += a2*wA[1] + a1*wA[3] + b2*wB[1] + b1v*wB[3];
    acc3 += a3*wA[0] + a2*wA[2] + b3*wB[0] + b2*wB[2];
  }
  float bv = b1[0];
  fl4 o4 = {acc0+bv, acc1+bv, acc2+bv, acc3+bv};
  *(fl4*)(out_bt + (size_t)oy*224 + ox0) = o4;
}

__global__ __launch_bounds__(256) void k_resize(const float* __restrict__ m3, float* __restrict__ out_mask, int btbase){
  int cb = blockIdx.x;
  const float* in_bt = m3 + (size_t)cb*50176;
  int idx = blockIdx.y*256 + threadIdx.x;
  if (idx >= 90000) return;
  int oy = idx/300, ox = idx - oy*300;
  const float sc = 224.f/300.f;
  float sy = (oy+0.5f)*sc - 0.5f;
  float sx = (ox+0.5f)*sc - 0.5f;
  float fy = floorf(sy), fx = floorf(sx);
  float wy = sy-fy, wx = sx-fx;
  int y0 = (int)fy, x0 = (int)fx;
  int y0c = min(max(y0,0),223), y1c = min(max(y0+1,0),223);
  int x0c = min(max(x0,0),223), x1c = min(max(x0+1,0),223);
  float v00 = in_bt[y0c*224+x0c], v01 = in_bt[y0c*224+x1c];
  float v10 = in_bt[y1c*224+x0c], v11 = in_bt[y1c*224+x1c];
  float v = (1.f-wy)*((1.f-wx)*v00 + wx*v01) + wy*((1.f-wx)*v10 + wx*v11);
  out_mask[(size_t)(btbase+cb)*90000 + idx] = v;
}

// ---------------------------------------------------------------- host

extern "C" void kernel_launch(void* const* d_in, const int* in_sizes, int n_in,
                              void* d_out, int out_size, void* d_ws, size_t ws_size,
                              hipStream_t stream)
{
  const float* enc      = (const float*)d_in[0];
  const float* frames   = (const float*)d_in[1];
  const float* gcn      = (const float*)d_in[2];
  const float* h0       = (const float*)d_in[3];
  const float* c0       = (const float*)d_in[4];
  const float* conv1_w  = (const float*)d_in[5];
  const float* conv1_b  = (const float*)d_in[6];
  const float* bn1_g    = (const float*)d_in[7];
  const float* bn1_b    = (const float*)d_in[8];
  const float* conv2_w  = (const float*)d_in[9];
  const float* conv2_b  = (const float*)d_in[10];
  const float* bn2_g    = (const float*)d_in[11];
  const float* bn2_b    = (const float*)d_in[12];
  const float* fc_w     = (const float*)d_in[13];
  const float* fc_b     = (const float*)d_in[14];
  const float* hfc_w    = (const float*)d_in[15];
  const float* hfc_b    = (const float*)d_in[16];
  const float* w_ih     = (const float*)d_in[17];
  const float* w_hh     = (const float*)d_in[18];
  const float* b_ih     = (const float*)d_in[19];
  const float* b_hh     = (const float*)d_in[20];
  const float* go       = (const float*)d_in[21];
  const float* emb_w    = (const float*)d_in[22];
  const float* actor_w  = (const float*)d_in[23];
  const float* actor_b  = (const float*)d_in[24];
  const float* d1_w     = (const float*)d_in[25];
  const float* d1_b     = (const float*)d_in[26];
  const float* dconv3_w = (const float*)d_in[27];
  const float* dconv3_b = (const float*)d_in[28];
  const float* bnm2_g   = (const float*)d_in[29];
  const float* bnm2_b   = (const float*)d_in[30];
  const float* dconv2_w = (const float*)d_in[31];
  const float* dconv2_b = (const float*)d_in[32];
  const float* bnm1_g   = (const float*)d_in[33];
  const float* bnm1_b   = (const float*)d_in[34];
  const float* dconv1_w = (const float*)d_in[35];
  const float* dconv1_b = (const float*)d_in[36];
  (void)in_sizes; (void)n_in; (void)out_size;

  // ---- output layout (float element offsets)
  float* obase    = (float*)d_out;
  float* out_act  = obase;                // 196608
  float* out_mask = obase + 196608;       // 17280000 (69.12 MB — scratch arena until decode)
  float* out_attn = obase + 17476608;     // 27840
  float* out_h    = obase + 17504448;     // 8192
  float* out_c    = obase + 17512640;     // 8192

  // ---- big scratch arena = out_mask region, written only by the final decode phase
  char* ob = (char*)out_mask;
  size_t ooff = 0;
  auto oalloc = [&](size_t bytes)->char*{ char* p = ob + ooff; ooff = (ooff + bytes + 255) & ~(size_t)255; return p; };
  // live through the loop:
  u16*   wseq      = (u16*)  oalloc(4096ULL*2176*2);    // 17.8 MB
  u16*   dseq      = (u16*)  oalloc(3264ULL*2176*2);    // 14.2 MB
  float* encH      = (float*)oalloc(1160ULL*1024*4);    // 4.75 MB
  float* gates_pre = (float*)oalloc(192ULL*4096*4);     // 3.15 MB
  float* d1a_pre   = (float*)oalloc(192ULL*3264*4);     // 2.51 MB
  u16*   xin2      = (u16*)  oalloc(192ULL*3072*2);     // 1.18 MB (dead after pre-GEMMs)
  // transient conv-chain zone (dead before the loop starts):
  u16*   XT     = (u16*)oalloc(12288ULL*512*2);         // 12.6 MB
  u16*   Y1     = (u16*)oalloc(12288ULL*256*2);         // 6.3 MB
  u16*   Y2     = (u16*)oalloc(12288ULL*64*2);          // 1.6 MB
  u16*   vis_in = (u16*)oalloc(192ULL*3136*2);          // 1.2 MB
  u16*   vis    = (u16*)oalloc(192ULL*2500*2);          // 0.96 MB
  u16*   wchunk = XT;  // pre-GEMM weight chunk aliases XT (dead by then); 6.3MB <= 12.6MB
  // total ~66.3 MB <= 69.12 MB

  // ---- ws: small persistent state + d1a_out + hfcT/decode-chunk alias zone
  char* wsb = (char*)d_ws;
  size_t off = 0;
  auto alloc = [&](size_t bytes)->char*{ char* p = wsb + off; off = (off + bytes + 255) & ~(size_t)255; return p; };
  float* d1a_out   = (float*)alloc(192ULL*3264*4);      // 2.5 MB, read by decode
  u16*   embT      = (u16*)  alloc(128ULL*1024*2);
  float* eb        = (float*)alloc(1160ULL*4);
  u16*   Wt3       = (u16*)  alloc(128ULL*576*2);
  u16*   Wt2       = (u16*)  alloc(64ULL*288*2);
  u16*   Wt1       = (u16*)  alloc(16ULL*160*2);
  float* hb        = (float*)alloc(2ULL*8192*4);
  float* c_ws      = (float*)alloc(8192ULL*4);
  float* e_cur     = (float*)alloc(8ULL*128*4);
  float* weighted  = (float*)alloc(8192ULL*4);
  float* scores_raw= (float*)alloc(8ULL*145*4);
  float* cmv       = (float*)alloc(32ULL*4);
  int*   cmi       = (int*)  alloc(32ULL*4);
  float* bias_g    = (float*)alloc(4096ULL*4);
  float* bias_da   = (float*)alloc(3264ULL*4);
  u16*   xb1       = (u16*)  alloc(8ULL*2176*2);        // packed [h|wgt|e] (hcur)
  u16*   xb2       = (u16*)  alloc(8ULL*2176*2);        // packed [h|wgt|e] (hnew)
  float* gates4    = (float*)alloc(8ULL*4096*4);        // per-step gates
  size_t zbase = off;
  u16*   hfcT = (u16*)alloc(1024ULL*1024*2);            // dead after encH gemm

  // decode chunk buffers alias hfcT zone; per-bt = 1,455,104 B
  const int cands[10] = {48,24,16,12,8,6,4,3,2,1};
  int C = 1;
  for (int i=0;i<10;i++){
    size_t need = zbase + (size_t)cands[i]*1455104ULL + 65536;
    if (need <= ws_size){ C = cands[i]; break; }
  }
  size_t mo = zbase;
  auto malloc_ = [&](size_t bytes)->char*{ char* p = wsb + mo; mo = (mo + bytes + 255) & ~(size_t)255; return p; };
  float* m0up = (float*)malloc_((size_t)C*12544*4);
  float* m1up = (float*)malloc_((size_t)C*32*3136*4);
  float* m2b  = (float*)malloc_((size_t)C*16*12544*4);
  float* m3b  = (float*)malloc_((size_t)C*50176*4);

  // ---- upfront packs
  k_pack_frames<<<192, 256, 0, stream>>>(frames, XT);
  k_pack_wseq<<<4096, 256, 0, stream>>>(w_ih, w_hh, wseq);
  k_pack_dseq<<<3264, 256, 0, stream>>>(d1_w, actor_w, dseq);
  k_hfcT<<<4096, 256, 0, stream>>>(hfc_w, hfcT);
  k_misc<<<758, 256, 0, stream>>>(b_ih, b_hh, d1_b, actor_b, emb_w, h0, c0,
                                  dconv3_w, dconv2_w, dconv1_w,
                                  bias_g, bias_da, embT, hb, c_ws, Wt3, Wt2, Wt1);
  k_eb<<<290, 256, 0, stream>>>(enc, hfc_b, eb);

  // ---- upfront GEMMs (vis encoder chain + encH)
  gemm64<1,1><<<dim3(192,4), 256, 0, stream>>>(XT, 512, conv1_w, 512, Y1, 256, 12288, 256, 512, nullptr, conv1_b, bn1_g, bn1_b);
  gemm64<1,1><<<dim3(192,1), 256, 0, stream>>>(Y1, 256, conv2_w, 256, Y2, 64, 12288, 64, 256, nullptr, conv2_b, bn2_g, bn2_b);
  k_vis_in<<<192, 256, 0, stream>>>(Y2, vis_in);
  gemm16<1><<<dim3(12,157), 64, 0, stream>>>(vis_in, 3136, fc_w, 3136, vis, 2500, 192, 2500, 3136, fc_b);
  k_xin<<<192, 256, 0, stream>>>(vis, gcn, xin2);
  gemm16<0><<<dim3(73,64), 64, 0, stream>>>(enc, 1024, hfcT, 1024, encH, 1024, 1160, 1024, 1024, nullptr);

  // ---- pre-GEMMs for the (vis|gcn) columns, N-chunked (wchunk aliases XT, now dead)
  for (int c=0;c<4;c++){
    k_pack_wvg<<<1024, 256, 0, stream>>>(w_ih, wchunk, c*1024);
    gemm16<0><<<dim3(12,64), 64, 0, stream>>>(xin2, 3072, wchunk, 3072, gates_pre + c*1024, 4096,
                                              192, 1024, 3072, bias_g + c*1024);
  }
  for (int c=0;c<3;c++){
    k_pack_dvg<<<1088, 256, 0, stream>>>(d1_w, actor_w, wchunk, c*1088);
    gemm16<0><<<dim3(12,68), 64, 0, stream>>>(xin2, 3072, wchunk, 3072, d1a_pre + c*1088, 3264,
                                              192, 1088, 3072, bias_da + c*1088);
  }

  // ---- sequential loop
  for (int t=0; t<=24; t++){
    float* hcur = hb + (t&1)*8192;
    float* hnew = hb + ((t+1)&1)*8192;
    p1_scores_action<<<80, 256, 0, stream>>>(encH, eb, hcur, c_ws, scores_raw, d1a_out, embT,
                                             out_act, cmv, cmi, out_h, out_c, xb1, t);
    if (t == 24) break;
    p2_softmax_weighted<<<64, 256, 0, stream>>>(scores_raw, enc, weighted, e_cur, cmv, cmi, emb_w, go,
                                                out_attn, xb1, xb2, t);
    p3m<<<256, 64, 0, stream>>>(wseq, xb1, gates4);
    p3l<<<32, 256, 0, stream>>>(gates4, gates_pre, hnew, c_ws, xb2, t);
    p4m<<<204, 64, 0, stream>>>(dseq, xb2, d1a_pre, d1a_out, t);
  }

  // ---- mask decode (192/C chunks of C bt) — overwrites the out-scratch arena, reads only d1a_out (ws)
  for (int btbase=0; btbase<192; btbase+=C){
    k_m0up<<<dim3(C,49), 256, 0, stream>>>(d1a_out, m0up, btbase);
    md3_deconv<<<dim3(C,2,13), 256, 0, stream>>>(m0up, m1up, Wt3, dconv3_b, bnm2_g, bnm2_b);
    md2_deconv<<<dim3(C,196), 256, 0, stream>>>(m1up, m2b, Wt2, dconv2_b, bnm1_g, bnm1_b);
    md1_direct<<<dim3(C,49), 256, 0, stream>>>(m2b, m3b, dconv1_w, dconv1_b);
    k_resize<<<dim3(C,352), 256, 0, stream>>>(m3b, out_mask, btbase);
  }
}

// Round 4
// 3137.216 us; speedup vs baseline: 1.9123x; 1.0475x over previous
//
#include <hip/hip_runtime.h>
#include <cstdint>
#include <cstddef>

#define DEV __device__ __forceinline__
typedef short bf16x8 __attribute__((ext_vector_type(8)));
typedef float fl4 __attribute__((ext_vector_type(4)));
typedef float f32x4 __attribute__((ext_vector_type(4)));
typedef unsigned short u16;

#define BN_INV 0.9999950000375f

DEV float b2f(u16 u){ return __uint_as_float(((unsigned)u)<<16); }
DEV u16 f2b(float f){ unsigned u = __float_as_uint(f); unsigned r = (u + 0x7FFFu + ((u>>16)&1u))>>16; return (u16)r; }

DEV bf16x8 load8(const u16* p){ return *(const bf16x8*)p; }
DEV bf16x8 load8(const float* p){
  fl4 a = *(const fl4*)p; fl4 b = *(const fl4*)(p+4);
  bf16x8 r;
  r[0]=(short)f2b(a[0]); r[1]=(short)f2b(a[1]); r[2]=(short)f2b(a[2]); r[3]=(short)f2b(a[3]);
  r[4]=(short)f2b(b[0]); r[5]=(short)f2b(b[1]); r[6]=(short)f2b(b[2]); r[7]=(short)f2b(b[3]);
  return r;
}

// ---------------------------------------------------------------- pack kernels

// frames [192][512][49] f32 -> XT [192*64][512] bf16 (rows p>=49 zero)
__global__ __launch_bounds__(256) void k_pack_frames(const float* __restrict__ fr, u16* __restrict__ XT){
  int bt = blockIdx.x, tid = threadIdx.x;
  for (int e=0;e<128;e++){
    int flat = e*256 + tid;           // < 32768
    int p = flat>>9, c = flat&511;
    u16 v = 0;
    if (p < 49) v = f2b(fr[((size_t)bt*512 + c)*49 + p]);
    XT[((size_t)bt*64 + p)*512 + c] = v;
  }
}

// wseq [4096][2176] bf16 = [w_hh | w_ih cols 2500:3652]
__global__ __launch_bounds__(256) void k_pack_wseq(const float* __restrict__ w_ih, const float* __restrict__ w_hh,
                                                   u16* __restrict__ wseq){
  int r = blockIdx.x, tid = threadIdx.x;
  const float* wr = w_ih + (size_t)r*4164;
  for (int j=tid;j<2176;j+=256){
    float v = (j < 1024) ? w_hh[(size_t)r*1024 + j] : wr[2500 + (j-1024)];
    wseq[(size_t)r*2176 + j] = f2b(v);
  }
}

// dseq [3264][2176] bf16 = [dw cols 0:1024 | dw cols 3524:4676]  (rows 0:3136 d1_w, then actor_w)
__global__ __launch_bounds__(256) void k_pack_dseq(const float* __restrict__ d1_w, const float* __restrict__ actor_w,
                                                   u16* __restrict__ dseq){
  int r = blockIdx.x, tid = threadIdx.x;
  const float* wr = (r < 3136) ? (d1_w + (size_t)r*5188) : (actor_w + (size_t)(r-3136)*5188);
  for (int j=tid;j<2176;j+=256){
    float v = (j < 1024) ? wr[j] : wr[3524 + (j-1024)];
    dseq[(size_t)r*2176 + j] = f2b(v);
  }
}

// wvg chunk [2048][3072] bf16 = [w_ih cols 0:2500 | w_ih cols 3652:4164 | 0]
__global__ __launch_bounds__(256) void k_pack_wvg(const float* __restrict__ w_ih, u16* __restrict__ wvg, int rbase){
  int r = rbase + blockIdx.x, tid = threadIdx.x;
  const float* wr = w_ih + (size_t)r*4164;
  u16* dst = wvg + (size_t)blockIdx.x*3072;
  for (int j=tid;j<3072;j+=256){
    float v = 0.f;
    if (j < 2500) v = wr[j];
    else if (j < 3012) v = wr[3652 + (j-2500)];
    dst[j] = f2b(v);
  }
}

// dvg chunk [1632][3072] bf16 = [dw cols 1024:3524 | dw cols 4676:5188 | 0]
__global__ __launch_bounds__(256) void k_pack_dvg(const float* __restrict__ d1_w, const float* __restrict__ actor_w,
                                                  u16* __restrict__ dvg, int rbase){
  int r = rbase + blockIdx.x, tid = threadIdx.x;
  const float* wr = (r < 3136) ? (d1_w + (size_t)r*5188) : (actor_w + (size_t)(r-3136)*5188);
  u16* dst = dvg + (size_t)blockIdx.x*3072;
  for (int j=tid;j<3072;j+=256){
    float v = 0.f;
    if (j < 2500) v = wr[1024 + j];
    else if (j < 3012) v = wr[4676 + (j-2500)];
    dst[j] = f2b(v);
  }
}

__global__ __launch_bounds__(256) void k_hfcT(const float* __restrict__ hfc_w, u16* __restrict__ hfcT){
  int idx = blockIdx.x*256 + threadIdx.x;   // 1M
  int k = idx>>10, o = idx&1023;
  hfcT[idx] = f2b(hfc_w[o*1024 + k]);
}

DEV u16 wt_map(const float* w, int n, int k, int CIN, int COUT){
  int o = n % COUT; int cls = n / COUT;
  if (cls >= 4) return 0;
  int py = cls>>1, px = cls&1;
  int i = k/9; int dd = k - i*9; int dy = dd/3, dx = dd - dy*3;
  if (i >= CIN) return 0;
  int ky = (py==0) ? (dy==0 ? 3 : (dy==1 ? 1 : -1)) : (dy==1 ? 2 : (dy==2 ? 0 : -1));
  int kx = (px==0) ? (dx==0 ? 3 : (dx==1 ? 1 : -1)) : (dx==1 ? 2 : (dx==2 ? 0 : -1));
  if (ky < 0 || kx < 0) return 0;
  return f2b(w[((i*COUT + o)*4 + ky)*4 + kx]);
}

__global__ __launch_bounds__(256) void k_misc(
  const float* b_ih, const float* b_hh, const float* d1_b, const float* actor_b,
  const float* emb_w, const float* h0, const float* c0,
  const float* dw3, const float* dw2, const float* dw1,
  float* bias_g, float* bias_da, u16* embT, float* hb0, float* cws,
  u16* Wt3, u16* Wt2, u16* Wt1)
{
  int blk = blockIdx.x, tid = threadIdx.x;
  if (blk < 16){ int i = blk*256+tid; if (i<4096) bias_g[i] = b_ih[i] + b_hh[i]; }
  else if (blk < 29){ int i = (blk-16)*256+tid; if (i<3264) bias_da[i] = (i<3136)? d1_b[i] : actor_b[i-3136]; }
  else if (blk < 541){ int i = (blk-29)*256+tid; int j = i>>10, v = i&1023; embT[i] = f2b(emb_w[v*128 + j]); }
  else if (blk < 573){ int i = (blk-541)*256+tid; if (i<8192){ hb0[i] = h0[i]; cws[i] = c0[i]; } }
  else if (blk < 574){ for (int i=tid;i<2560;i+=256){ int n=i/160, k=i-n*160; Wt1[i] = wt_map(dw1,n,k,16,1); } }
  else if (blk < 590){ for (int i=(blk-574)*256+tid; i<18432; i+=16*256){ int n=i/288, k=i-n*288; Wt2[i] = wt_map(dw2,n,k,32,16); } }
  else { for (int i=(blk-590)*256+tid; i<73728; i+=168*256){ int n=i/576, k=i-n*576; Wt3[i] = wt_map(dw3,n,k,64,32); } }
}

__global__ __launch_bounds__(256) void k_eb(const float* __restrict__ enc, const float* __restrict__ hfc_b, float* __restrict__ eb){
  int li = blockIdx.x*4 + (threadIdx.x>>6);
  int lane = threadIdx.x & 63;
  if (li >= 1160) return;
  const float* ep = enc + (size_t)li*1024;
  float a = 0.f;
  for (int k=lane;k<1024;k+=64) a += ep[k]*hfc_b[k];
  #pragma unroll
  for (int off=32; off; off>>=1) a += __shfl_xor(a, off);
  if (lane == 0) eb[li] = a;
}

// Y2 [192*64][64] bf16 -> vis_in [192][3136] bf16 (c*49+p ordering)
__global__ __launch_bounds__(256) void k_vis_in(const u16* __restrict__ Y2, u16* __restrict__ vis_in){
  int bt = blockIdx.x, tid = threadIdx.x;
  for (int f=tid; f<3136; f+=256){
    int c = f/49, p = f - c*49;
    vis_in[(size_t)bt*3136 + f] = Y2[((size_t)bt*64 + p)*64 + c];
  }
}

// xin2 [192][3072] bf16 = [vis 2500 | gcn 512 | 0]
__global__ __launch_bounds__(256) void k_xin(const u16* __restrict__ vis, const float* __restrict__ gcn, u16* __restrict__ xin2){
  int bt = blockIdx.x, tid = threadIdx.x, b = bt/24;
  for (int j=tid;j<3072;j+=256){
    u16 v = 0;
    if (j < 2500) v = vis[(size_t)bt*2500 + j];
    else if (j < 3012) v = f2b(gcn[b*512 + (j-2500)]);
    xin2[(size_t)bt*3072 + j] = v;
  }
}

// ---------------------------------------------------------------- generic MFMA GEMM (C[M,N] = A[M,K] @ B[N,K]^T)
// 64x64-tile version (used for the conv chain); k-slices of 32, increasing.
template<int OUTB, int ACT, typename TA, typename TB>
__global__ __launch_bounds__(256) void gemm64(
  const TA* __restrict__ A, int lda, const TB* __restrict__ Bm, int ldb,
  void* __restrict__ Cv, int ldc, int M, int N, int K,
  const float* __restrict__ bias, const float* __restrict__ cb, const float* __restrict__ gg, const float* __restrict__ bb)
{
  __shared__ u16 sA[64*72];
  __shared__ u16 sB[64*72];
  int tid = threadIdx.x, lane = tid & 63, w = tid >> 6;
  int wm = w & 1, wn = w >> 1;
  int m0 = blockIdx.x*64, n0 = blockIdx.y*64;
  f32x4 acc[2][2];
  #pragma unroll
  for (int a=0;a<2;a++)
    #pragma unroll
    for (int b=0;b<2;b++){ acc[a][b][0]=0;acc[a][b][1]=0;acc[a][b][2]=0;acc[a][b][3]=0; }

  for (int k0=0;k0<K;k0+=64){
    #pragma unroll
    for (int j=0;j<2;j++){
      int c = tid + 256*j; int row = c>>3; int col = (c&7)*8;
      bf16x8 va = {0,0,0,0,0,0,0,0};
      int gm = m0 + row;
      if (gm < M) va = load8(A + (size_t)gm*lda + k0 + col);
      *(bf16x8*)(&sA[row*72 + col]) = va;
      bf16x8 vb = {0,0,0,0,0,0,0,0};
      int gn = n0 + row;
      if (gn < N) vb = load8(Bm + (size_t)gn*ldb + k0 + col);
      *(bf16x8*)(&sB[row*72 + col]) = vb;
    }
    __syncthreads();
    #pragma unroll
    for (int kk=0;kk<2;kk++){
      bf16x8 af[2], bfv[2];
      #pragma unroll
      for (int tm=0;tm<2;tm++) af[tm]  = *(const bf16x8*)(&sA[(wm*32+tm*16+(lane&15))*72 + kk*32 + (lane>>4)*8]);
      #pragma unroll
      for (int tn=0;tn<2;tn++) bfv[tn] = *(const bf16x8*)(&sB[(wn*32+tn*16+(lane&15))*72 + kk*32 + (lane>>4)*8]);
      #pragma unroll
      for (int tm=0;tm<2;tm++)
        #pragma unroll
        for (int tn=0;tn<2;tn++)
          acc[tm][tn] = __builtin_amdgcn_mfma_f32_16x16x32_bf16(af[tm], bfv[tn], acc[tm][tn], 0,0,0);
    }
    __syncthreads();
  }
  int ml = (lane>>4)*4, nl = lane&15;
  #pragma unroll
  for (int tm=0;tm<2;tm++)
    #pragma unroll
    for (int tn=0;tn<2;tn++)
      #pragma unroll
      for (int r=0;r<4;r++){
        int gm = m0 + wm*32 + tm*16 + ml + r;
        int gn = n0 + wn*32 + tn*16 + nl;
        if (gm < M && gn < N){
          float v = acc[tm][tn][r];
          if (ACT == 0){ if (bias) v += bias[gn]; }
          else { v = (v + cb[gn])*BN_INV*gg[gn] + bb[gn]; v = fmaxf(v, 0.f); }
          if (OUTB) ((u16*)Cv)[(size_t)gm*ldc + gn] = f2b(v);
          else      ((float*)Cv)[(size_t)gm*ldc + gn] = v;
        }
      }
}

// 16x16-tile 1-wave GEMM with bijective XCD-swizzle.  Bitwise-identical per-output
// accumulation chain (increasing k-slices of 32, same f2b operand conversion).
// NMAJOR=1: contiguous block ids (one XCD) cluster on n-tiles (share B);
// NMAJOR=0: cluster on m-tiles (share A).
template<int OUTB, int NMAJOR, typename TA, typename TB>
__global__ __launch_bounds__(64) void gemm16x(
  const TA* __restrict__ A, int lda, const TB* __restrict__ Bm, int ldb,
  void* __restrict__ Cv, int ldc, int M, int N, int K, const float* __restrict__ bias,
  int MT, int NT)
{
  int nb = gridDim.x;
  int orig = blockIdx.x;
  int q = nb >> 3, r = nb & 7;
  int xcd = orig & 7, j = orig >> 3;
  int wg = (xcd < r ? xcd*(q+1) : r*(q+1) + (xcd-r)*q) + j;
  int bx, by;
  if (NMAJOR){ bx = wg % MT; by = wg / MT; }
  else       { by = wg % NT; bx = wg / NT; }
  int lane = threadIdx.x;
  int m0 = bx*16, n0 = by*16;
  int gm = m0 + (lane&15); if (gm > M-1) gm = M-1;   // clamp: rows >=M never stored
  int gn = n0 + (lane&15); if (gn > N-1) gn = N-1;   // clamp: cols >=N never stored
  const TA* ap = A  + (size_t)gm*lda + ((lane>>4)*8);
  const TB* bp = Bm + (size_t)gn*ldb + ((lane>>4)*8);
  f32x4 acc = {0,0,0,0};
  #pragma unroll 4
  for (int ks=0; ks<K; ks+=32){
    bf16x8 a = load8(ap + ks);
    bf16x8 b = load8(bp + ks);
    acc = __builtin_amdgcn_mfma_f32_16x16x32_bf16(a, b, acc, 0,0,0);
  }
  int nn = n0 + (lane&15);
  if (nn >= N) return;
  #pragma unroll
  for (int r2=0;r2<4;r2++){
    int mm = m0 + (lane>>4)*4 + r2;
    if (mm < M){
      float v = acc[r2];
      if (bias) v += bias[nn];
      if (OUTB) ((u16*)Cv)[(size_t)mm*ldc + nn] = f2b(v);
      else      ((float*)Cv)[(size_t)mm*ldc + nn] = v;
    }
  }
}

// ---------------------------------------------------------------- per-step kernels

// P1: scores (blocks 0-39) + action/argmax of t-1 (40-71) + h-pack / h,c output (72-79)
__global__ __launch_bounds__(256) void p1_scores_action(
  const float* __restrict__ encH, const float* __restrict__ eb,
  const float* __restrict__ hcur, const float* __restrict__ cws,
  float* __restrict__ scores, const float* __restrict__ d1a_out,
  const u16* __restrict__ embT, float* __restrict__ out_act,
  float* __restrict__ cmv, int* __restrict__ cmi,
  float* __restrict__ out_h, float* __restrict__ out_c,
  u16* __restrict__ xb1, int t)
{
  __shared__ float shf[1024];
  __shared__ int shi[256];
  int blk = blockIdx.x, tid = threadIdx.x;
  if (blk < 40){
    if (t == 24) return;
    int b = blk/5, lc = blk - b*5;
    #pragma unroll
    for (int e=0;e<4;e++) shf[tid + 256*e] = hcur[b*1024 + tid + 256*e];
    __syncthreads();
    int w = tid>>6, lane = tid&63;
    for (int i=w;i<29;i+=4){
      int l = lc*29 + i;
      const float* ep = encH + (size_t)(b*145+l)*1024;
      float a = 0.f;
      for (int k=lane;k<1024;k+=64) a += ep[k]*shf[k];
      #pragma unroll
      for (int off=32; off; off>>=1) a += __shfl_xor(a, off);
      if (lane == 0) scores[b*145+l] = a + eb[b*145+l];
    }
  } else if (blk < 72){
    if (t == 0) return;
    int idx = blk-40; int b = idx>>2, vc = idx&3;
    if (tid < 128) shf[tid] = d1a_out[(size_t)(b*24 + t-1)*3264 + 3136 + tid];
    __syncthreads();
    int v = vc*256 + tid;
    float a = 0.f;
    for (int j=0;j<128;j++) a += shf[j]*b2f(embT[j*1024 + v]);
    out_act[(size_t)(b*24 + t-1)*1024 + v] = a;
    shf[256+tid] = a; shi[tid] = v;
    __syncthreads();
    for (int s=128; s; s>>=1){
      if (tid < s){
        float o = shf[256+tid+s]; int oi = shi[tid+s];
        float c = shf[256+tid];   int ci = shi[tid];
        if (o > c || (o == c && oi < ci)){ shf[256+tid] = o; shi[tid] = oi; }
      }
      __syncthreads();
    }
    if (tid == 0){ cmv[b*4+vc] = shf[256]; cmi[b*4+vc] = shi[0]; }
  } else {
    int b = blk-72;
    if (t == 24){
      #pragma unroll
      for (int e=0;e<4;e++){
        int k = tid + 256*e;
        out_h[b*1024+k] = hcur[b*1024+k];
        out_c[b*1024+k] = cws[b*1024+k];
      }
    } else {
      #pragma unroll
      for (int e=0;e<4;e++){
        int k = tid + 256*e;
        xb1[b*2176 + k] = f2b(hcur[b*1024+k]);
      }
    }
  }
}

// P2: softmax + weighted + attn-out + e selection; also packs wgt/e slices into xb1/xb2
__global__ __launch_bounds__(256) void p2_softmax_weighted(
  const float* __restrict__ scores, const float* __restrict__ enc,
  float* __restrict__ wgt, float* __restrict__ ecur,
  const float* __restrict__ cmv, const int* __restrict__ cmi,
  const float* __restrict__ emb_w, const float* __restrict__ go,
  float* __restrict__ out_attn, u16* __restrict__ xb1, u16* __restrict__ xb2, int t)
{
  int b = blockIdx.x >> 3, dc = blockIdx.x & 7, tid = threadIdx.x;
  __shared__ float s[145];
  __shared__ float mxs, invs;
  if (tid < 145) s[tid] = scores[b*145+tid];
  __syncthreads();
  if (tid < 64){
    float m = -1e30f;
    for (int i=tid;i<145;i+=64) m = fmaxf(m, s[i]);
    #pragma unroll
    for (int off=32; off; off>>=1) m = fmaxf(m, __shfl_xor(m, off));
    if (tid == 0) mxs = m;
  }
  __syncthreads();
  if (tid < 145) s[tid] = expf(s[tid]-mxs);
  __syncthreads();
  if (tid < 64){
    float sm = 0.f;
    for (int i=tid;i<145;i+=64) sm += s[i];
    #pragma unroll
    for (int off=32; off; off>>=1) sm += __shfl_xor(sm, off);
    if (tid == 0) invs = 1.f/sm;
  }
  __syncthreads();
  float inv = invs;
  if (tid < 128){
    int d = dc*128 + tid;
    float a = 0.f;
    for (int l=0;l<145;l++) a += s[l]*enc[(size_t)(b*145+l)*1024 + d];
    float wv = a*inv;
    wgt[b*1024+d] = wv;
    u16 wb = f2b(wv);
    xb1[b*2176 + 1024 + d] = wb;
    xb2[b*2176 + 1024 + d] = wb;
  } else {
    int i = tid-128;
    if (dc == 0){
      if (i < 145) out_attn[(size_t)(b*24+t)*145 + i] = s[i]*inv;
      int l2 = i + 128;
      if (l2 < 145) out_attn[(size_t)(b*24+t)*145 + l2] = s[l2]*inv;
    } else if (dc == 1){
      float ev;
      if (t == 0) ev = go[i];
      else {
        float bv = cmv[b*4]; int bi = cmi[b*4];
        #pragma unroll
        for (int c=1;c<4;c++){
          float v2 = cmv[b*4+c]; int i2 = cmi[b*4+c];
          if (v2 > bv || (v2 == bv && i2 < bi)){ bv = v2; bi = i2; }
        }
        ev = emb_w[bi*128 + i];
      }
      ecur[b*128+i] = ev;
      u16 eb16 = f2b(ev);
      xb1[b*2176 + 2048 + i] = eb16;
      xb2[b*2176 + 2048 + i] = eb16;
    }
  }
}

// P3m: gates GEMM, one wave per 16 output cols; bitwise-identical 68-MFMA chain.
__global__ __launch_bounds__(64) void p3m(
  const u16* __restrict__ wseq, const u16* __restrict__ xb, float* __restrict__ gates4)
{
  int lane = threadIdx.x;
  int n = blockIdx.x*16 + (lane & 15);
  const u16* bp = wseq + (size_t)n*2176 + ((lane>>4)*8);
  const u16* ap = xb + (lane&7)*2176 + ((lane>>4)*8);
  f32x4 acc = {0,0,0,0};
  #pragma unroll 4
  for (int kk=0;kk<68;kk++){
    bf16x8 a = *(const bf16x8*)(ap + kk*32);
    bf16x8 b = *(const bf16x8*)(bp + kk*32);
    acc = __builtin_amdgcn_mfma_f32_16x16x32_bf16(a, b, acc, 0,0,0);
  }
  #pragma unroll
  for (int r=0;r<4;r++){
    int m = (lane>>4)*4 + r;
    if (m < 8) gates4[(size_t)m*4096 + n] = acc[r];
  }
}

// P3l: LSTM elementwise; packs hnew into xb2.
__global__ __launch_bounds__(256) void p3l(
  const float* __restrict__ gates4, const float* __restrict__ gpre,
  float* __restrict__ hnew, float* __restrict__ cws, u16* __restrict__ xb2, int t)
{
  int idx = blockIdx.x*256 + threadIdx.x;   // 8192
  int b = idx>>10, J = idx&1023;
  const float* gp = gpre + (size_t)(b*24+t)*4096;
  const float* gb = gates4 + (size_t)b*4096;
  float iv = gb[J]      + gp[J];
  float fv = gb[1024+J] + gp[1024+J];
  float gv = gb[2048+J] + gp[2048+J];
  float ov = gb[3072+J] + gp[3072+J];
  float ig = 1.f/(1.f+expf(-iv));
  float fg = 1.f/(1.f+expf(-fv));
  float gt = tanhf(gv);
  float og = 1.f/(1.f+expf(-ov));
  float cn = fg*cws[idx] + ig*gt;
  cws[idx] = cn;
  float hv = og*tanhf(cn);
  hnew[idx] = hv;
  xb2[b*2176 + J] = f2b(hv);
}

// P4m: d1+actor GEMM, one wave per 16 output cols. grid 204 x 64.
__global__ __launch_bounds__(64) void p4m(
  const u16* __restrict__ dseq, const u16* __restrict__ xb2,
  const float* __restrict__ dpre, float* __restrict__ dout, int t)
{
  int lane = threadIdx.x;
  int R = blockIdx.x*16 + (lane & 15);
  const u16* bp = dseq + (size_t)R*2176 + ((lane>>4)*8);
  const u16* ap = xb2 + (lane&7)*2176 + ((lane>>4)*8);
  f32x4 acc = {0,0,0,0};
  #pragma unroll 4
  for (int kk=0;kk<68;kk++){
    bf16x8 a = *(const bf16x8*)(ap + kk*32);
    bf16x8 b = *(const bf16x8*)(bp + kk*32);
    acc = __builtin_amdgcn_mfma_f32_16x16x32_bf16(a, b, acc, 0,0,0);
  }
  #pragma unroll
  for (int r=0;r<4;r++){
    int m = (lane>>4)*4 + r;
    if (m < 8){
      size_t row = (size_t)(m*24+t)*3264;
      dout[row + R] = acc[r] + dpre[row + R];
    }
  }
}

// ---------------------------------------------------------------- mask decode

// stage for deconv3: read straight from d1a_out (fold up2 7->14 + relu).
DEV void stage_tile3(u16* sAt, const float* __restrict__ d1a_bt, int p0, int tid){
  int m = tid & 15;
  int p = p0 + m;
  int u = p / 14, v = p - u*14;
  bool pv = p < 196;
  for (int k = tid>>4; k < 576; k += 16){
    float val = 0.f;
    if (pv){
      int i = k/9; int dd = k - i*9; int dy = dd/3, dx = dd - dy*3;
      int uy = u + dy - 1, vx = v + dx - 1;
      if (uy >= 0 && uy < 14 && vx >= 0 && vx < 14)
        val = fmaxf(d1a_bt[i*49 + (uy>>1)*7 + (vx>>1)], 0.f);
    }
    sAt[m*584 + k] = f2b(val);
  }
}

// stage for deconv2: read m1c [32][28][28] (fold up2 28->56).
DEV void stage_tile2(u16* sAt, const float* __restrict__ m1c_bt, int p0, int tid){
  int m = tid & 15;
  int p = p0 + m;
  int u = p / 56, v = p - u*56;
  bool pv = p < 3136;
  for (int k = tid>>4; k < 288; k += 16){
    float val = 0.f;
    if (pv){
      int i = k/9; int dd = k - i*9; int dy = dd/3, dx = dd - dy*3;
      int uy = u + dy - 1, vx = v + dx - 1;
      if (uy >= 0 && uy < 56 && vx >= 0 && vx < 56)
        val = m1c_bt[i*784 + (uy>>1)*28 + (vx>>1)];
    }
    sAt[m*296 + k] = f2b(val);
  }
}

// stage for deconv1 (unchanged layout, reads m2 at full res)
DEV void stage_tile(u16* sAt, int ldk, int Ktot, int Kreal, const float* in_bt, int H, int p0, int tid){
  int m = tid & 15;
  int p = p0 + m;
  int u = p / H, v = p - u*H;
  bool pv = p < H*H;
  for (int k = tid>>4; k < Ktot; k += 16){
    float val = 0.f;
    if (k < Kreal && pv){
      int i = k/9; int dd = k - i*9; int dy = dd/3, dx = dd - dy*3;
      int uy = u + dy - 1, vx = v + dx - 1;
      if (uy >= 0 && uy < H && vx >= 0 && vx < H) val = in_bt[((size_t)i*H + uy)*H + vx];
    }
    sAt[m*ldk + k] = f2b(val);
  }
}

// deconv3 (64->32, in-grid 14) -> m1c [32][28][28]; grid (C, 2, 13)
__global__ __launch_bounds__(256) void md3_deconv(const float* __restrict__ d1a_out, int btbase, float* __restrict__ m1c,
  const u16* __restrict__ Wt3, const float* __restrict__ b3, const float* __restrict__ g3, const float* __restrict__ bb3)
{
  __shared__ u16 sAt[16*584];
  int tid = threadIdx.x, lane = tid&63, w = tid>>6;
  int cb = blockIdx.x;
  const float* in_bt = d1a_out + (size_t)(btbase+cb)*3264;
  float* out_bt = m1c + (size_t)cb*32*784;
  int nt = blockIdx.y*4 + w;
  bf16x8 wc[18];
  #pragma unroll
  for (int ks=0;ks<18;ks++) wc[ks] = *(const bf16x8*)(Wt3 + (size_t)(nt*16 + (lane&15))*576 + ks*32 + (lane>>4)*8);
  int cls = nt>>1; int o = (nt&1)*16 + (lane&15);
  int py = cls>>1, px = cls&1;
  float cbv = b3[o], gv = g3[o], bbv = bb3[o];
  int mt = blockIdx.z;
  stage_tile3(sAt, in_bt, mt*16, tid);
  __syncthreads();
  f32x4 acc = {0,0,0,0};
  #pragma unroll
  for (int ks=0;ks<18;ks++){
    bf16x8 a = *(const bf16x8*)(&sAt[(lane&15)*584 + ks*32 + (lane>>4)*8]);
    acc = __builtin_amdgcn_mfma_f32_16x16x32_bf16(a, wc[ks], acc, 0,0,0);
  }
  #pragma unroll
  for (int r=0;r<4;r++){
    int p = mt*16 + (lane>>4)*4 + r;
    if (p < 196){
      int u = p/14, v = p - (p/14)*14;
      float vv = fmaxf((acc[r] + cbv)*BN_INV*gv + bbv, 0.f);
      out_bt[((size_t)o*28 + (2*u+py))*28 + (2*v+px)] = vv;
    }
  }
}

// deconv2 (32->16, in-grid 56 via folded up2 of m1c) -> m2 [16][112][112]; grid (C, 196)
__global__ __launch_bounds__(256) void md2_deconv(const float* __restrict__ m1c, float* __restrict__ m2,
  const u16* __restrict__ Wt2, const float* __restrict__ b2, const float* __restrict__ g2, const float* __restrict__ bb2)
{
  __shared__ u16 sAt[16*296];
  int tid = threadIdx.x, lane = tid&63, w = tid>>6;
  int cb = blockIdx.x;
  const float* in_bt = m1c + (size_t)cb*32*784;
  float* out_bt = m2 + (size_t)cb*16*12544;
  int nt = w;
  bf16x8 wc[9];
  #pragma unroll
  for (int ks=0;ks<9;ks++) wc[ks] = *(const bf16x8*)(Wt2 + (size_t)(nt*16 + (lane&15))*288 + ks*32 + (lane>>4)*8);
  int cls = nt; int o = lane&15;
  int py = cls>>1, px = cls&1;
  float cbv = b2[o], gv = g2[o], bbv = bb2[o];
  int mt = blockIdx.y;
  stage_tile2(sAt, in_bt, mt*16, tid);
  __syncthreads();
  f32x4 acc = {0,0,0,0};
  #pragma unroll
  for (int ks=0;ks<9;ks++){
    bf16x8 a = *(const bf16x8*)(&sAt[(lane&15)*296 + ks*32 + (lane>>4)*8]);
    acc = __builtin_amdgcn_mfma_f32_16x16x32_bf16(a, wc[ks], acc, 0,0,0);
  }
  #pragma unroll
  for (int r=0;r<4;r++){
    int p = mt*16 + (lane>>4)*4 + r;
    if (p < 3136){
      int u = p/56, v = p - u*56;
      float vv = fmaxf((acc[r] + cbv)*BN_INV*gv + bbv, 0.f);
      out_bt[((size_t)o*112 + (2*u+py))*112 + (2*v+px)] = vv;
    }
  }
}

// deconv1 (16->1, in-grid 112) -> m3 [224][224], direct fp32 VALU.
__global__ __launch_bounds__(256) void md1_direct(const float* __restrict__ m2, float* __restrict__ m3,
  const float* __restrict__ dw1, const float* __restrict__ b1)
{
  __shared__ float wl[256];               // dconv1_w: [i][ky][kx] = 16*4*4
  int tid = threadIdx.x;
  wl[tid] = dw1[tid];
  __syncthreads();
  int cb = blockIdx.x;
  const float* in_bt = m2 + (size_t)cb*16*12544;
  float* out_bt = m3 + (size_t)cb*50176;
  int idx = blockIdx.y*256 + tid;         // [0, 12544) : 224 rows x 56 quads
  int oy = idx/56, q = idx - oy*56;
  int ox0 = q*4;
  int iyA = (oy+1)>>1;  bool vA = iyA < 112;
  int iyB = iyA - 1;    bool vB = iyB >= 0;
  int kyA = (oy&1) ? 0 : 1;
  int kyB = kyA + 2;
  int xb = (ox0>>1) - 1;
  bool v0 = xb >= 0, v3 = (xb+3) < 112;
  int x0 = v0 ? xb : 0, x3 = v3 ? xb+3 : 111;
  float mA = vA ? 1.f : 0.f, mB = vB ? 1.f : 0.f;
  float mA0 = v0 ? mA : 0.f, mA3 = v3 ? mA : 0.f;
  float mB0 = v0 ? mB : 0.f, mB3 = v3 ? mB : 0.f;
  const float* rA = in_bt + (size_t)(vA ? iyA : 0)*112;
  const float* rB = in_bt + (size_t)(vB ? iyB : 0)*112;
  float acc0=0.f, acc1=0.f, acc2=0.f, acc3=0.f;
  #pragma unroll 4
  for (int i=0;i<16;i++){
    const float* cA = rA + i*12544;
    const float* cB = rB + i*12544;
    float a0 = cA[x0]*mA0, a1 = cA[xb+1]*mA, a2 = cA[xb+2]*mA, a3 = cA[x3]*mA3;
    float b0 = cB[x0]*mB0, b1v = cB[xb+1]*mB, b2 = cB[xb+2]*mB, b3 = cB[x3]*mB3;
    fl4 wA = *(const fl4*)(&wl[i*16 + kyA*4]);
    fl4 wB = *(const fl4*)(&wl[i*16 + kyB*4]);
    acc0 += a1*wA[1] + a0*wA[3] + b1v*wB[1] + b0*wB[3];
    acc1 += a2*wA[0] + a1*wA[2] + b2*wB[0] + b1v*wB[2];
    acc2 += a2*wA[1] + a1*wA[3] + b2*wB[1] + b1v*wB[3];
    acc3 += a3*wA[0] + a2*wA[2] + b3*wB[0] + b2*wB[2];
  }
  float bv = b1[0];
  fl4 o4 = {acc0+bv, acc1+bv, acc2+bv, acc3+bv};
  *(fl4*)(out_bt + (size_t)oy*224 + ox0) = o4;
}

__global__ __launch_bounds__(256) void k_resize(const float* __restrict__ m3, float* __restrict__ out_mask, int btbase){
  int cb = blockIdx.x;
  const float* in_bt = m3 + (size_t)cb*50176;
  int idx = blockIdx.y*256 + threadIdx.x;
  if (idx >= 90000) return;
  int oy = idx/300, ox = idx - oy*300;
  const float sc = 224.f/300.f;
  float sy = (oy+0.5f)*sc - 0.5f;
  float sx = (ox+0.5f)*sc - 0.5f;
  float fy = floorf(sy), fx = floorf(sx);
  float wy = sy-fy, wx = sx-fx;
  int y0 = (int)fy, x0 = (int)fx;
  int y0c = min(max(y0,0),223), y1c = min(max(y0+1,0),223);
  int x0c = min(max(x0,0),223), x1c = min(max(x0+1,0),223);
  float v00 = in_bt[y0c*224+x0c], v01 = in_bt[y0c*224+x1c];
  float v10 = in_bt[y1c*224+x0c], v11 = in_bt[y1c*224+x1c];
  float v = (1.f-wy)*((1.f-wx)*v00 + wx*v01) + wy*((1.f-wx)*v10 + wx*v11);
  out_mask[(size_t)(btbase+cb)*90000 + idx] = v;
}

// ---------------------------------------------------------------- host

extern "C" void kernel_launch(void* const* d_in, const int* in_sizes, int n_in,
                              void* d_out, int out_size, void* d_ws, size_t ws_size,
                              hipStream_t stream)
{
  const float* enc      = (const float*)d_in[0];
  const float* frames   = (const float*)d_in[1];
  const float* gcn      = (const float*)d_in[2];
  const float* h0       = (const float*)d_in[3];
  const float* c0       = (const float*)d_in[4];
  const float* conv1_w  = (const float*)d_in[5];
  const float* conv1_b  = (const float*)d_in[6];
  const float* bn1_g    = (const float*)d_in[7];
  const float* bn1_b    = (const float*)d_in[8];
  const float* conv2_w  = (const float*)d_in[9];
  const float* conv2_b  = (const float*)d_in[10];
  const float* bn2_g    = (const float*)d_in[11];
  const float* bn2_b    = (const float*)d_in[12];
  const float* fc_w     = (const float*)d_in[13];
  const float* fc_b     = (const float*)d_in[14];
  const float* hfc_w    = (const float*)d_in[15];
  const float* hfc_b    = (const float*)d_in[16];
  const float* w_ih     = (const float*)d_in[17];
  const float* w_hh     = (const float*)d_in[18];
  const float* b_ih     = (const float*)d_in[19];
  const float* b_hh     = (const float*)d_in[20];
  const float* go       = (const float*)d_in[21];
  const float* emb_w    = (const float*)d_in[22];
  const float* actor_w  = (const float*)d_in[23];
  const float* actor_b  = (const float*)d_in[24];
  const float* d1_w     = (const float*)d_in[25];
  const float* d1_b     = (const float*)d_in[26];
  const float* dconv3_w = (const float*)d_in[27];
  const float* dconv3_b = (const float*)d_in[28];
  const float* bnm2_g   = (const float*)d_in[29];
  const float* bnm2_b   = (const float*)d_in[30];
  const float* dconv2_w = (const float*)d_in[31];
  const float* dconv2_b = (const float*)d_in[32];
  const float* bnm1_g   = (const float*)d_in[33];
  const float* bnm1_b   = (const float*)d_in[34];
  const float* dconv1_w = (const float*)d_in[35];
  const float* dconv1_b = (const float*)d_in[36];
  (void)in_sizes; (void)n_in; (void)out_size;

  // ---- output layout (float element offsets)
  float* obase    = (float*)d_out;
  float* out_act  = obase;                // 196608
  float* out_mask = obase + 196608;       // 17280000 (69.12 MB — scratch arena until decode)
  float* out_attn = obase + 17476608;     // 27840
  float* out_h    = obase + 17504448;     // 8192
  float* out_c    = obase + 17512640;     // 8192

  // ---- big scratch arena = out_mask region, written only by the final decode phase
  char* ob = (char*)out_mask;
  size_t ooff = 0;
  auto oalloc = [&](size_t bytes)->char*{ char* p = ob + ooff; ooff = (ooff + bytes + 255) & ~(size_t)255; return p; };
  // live through the loop:
  u16*   wseq      = (u16*)  oalloc(4096ULL*2176*2);    // 17.8 MB
  u16*   dseq      = (u16*)  oalloc(3264ULL*2176*2);    // 14.2 MB
  float* encH      = (float*)oalloc(1160ULL*1024*4);    // 4.75 MB
  float* gates_pre = (float*)oalloc(192ULL*4096*4);     // 3.15 MB
  float* d1a_pre   = (float*)oalloc(192ULL*3264*4);     // 2.51 MB
  u16*   xin2      = (u16*)  oalloc(192ULL*3072*2);     // 1.18 MB (dead after pre-GEMMs)
  // transient conv-chain zone (dead before the loop starts):
  u16*   XT     = (u16*)oalloc(12288ULL*512*2);         // 12.6 MB
  u16*   Y1     = (u16*)oalloc(12288ULL*256*2);         // 6.3 MB
  u16*   Y2     = (u16*)oalloc(12288ULL*64*2);          // 1.6 MB
  u16*   vis_in = (u16*)oalloc(192ULL*3136*2);          // 1.2 MB
  u16*   vis    = (u16*)oalloc(192ULL*2500*2);          // 0.96 MB
  u16*   wchunk = XT;  // pre-GEMM weight chunk aliases XT (dead by then); 2048*3072*2=12.58MB <= 12.6MB
  // total ~66.3 MB <= 69.12 MB

  // ---- ws: small persistent state + d1a_out + hfcT/decode-chunk alias zone
  char* wsb = (char*)d_ws;
  size_t off = 0;
  auto alloc = [&](size_t bytes)->char*{ char* p = wsb + off; off = (off + bytes + 255) & ~(size_t)255; return p; };
  float* d1a_out   = (float*)alloc(192ULL*3264*4);      // 2.5 MB, read by decode
  u16*   embT      = (u16*)  alloc(128ULL*1024*2);
  float* eb        = (float*)alloc(1160ULL*4);
  u16*   Wt3       = (u16*)  alloc(128ULL*576*2);
  u16*   Wt2       = (u16*)  alloc(64ULL*288*2);
  u16*   Wt1       = (u16*)  alloc(16ULL*160*2);
  float* hb        = (float*)alloc(2ULL*8192*4);
  float* c_ws      = (float*)alloc(8192ULL*4);
  float* e_cur     = (float*)alloc(8ULL*128*4);
  float* weighted  = (float*)alloc(8192ULL*4);
  float* scores_raw= (float*)alloc(8ULL*145*4);
  float* cmv       = (float*)alloc(32ULL*4);
  int*   cmi       = (int*)  alloc(32ULL*4);
  float* bias_g    = (float*)alloc(4096ULL*4);
  float* bias_da   = (float*)alloc(3264ULL*4);
  u16*   xb1       = (u16*)  alloc(8ULL*2176*2);        // packed [h|wgt|e] (hcur)
  u16*   xb2       = (u16*)  alloc(8ULL*2176*2);        // packed [h|wgt|e] (hnew)
  float* gates4    = (float*)alloc(8ULL*4096*4);        // per-step gates
  size_t zbase = off;
  u16*   hfcT = (u16*)alloc(1024ULL*1024*2);            // dead after encH gemm

  // decode chunk buffers alias hfcT zone; per-bt = m1c 100352 + m2 802816 + m3 200704 = 1103872 B
  const int cands[10] = {48,24,16,12,8,6,4,3,2,1};
  int C = 1;
  for (int i=0;i<10;i++){
    size_t need = zbase + (size_t)cands[i]*1103872ULL + 65536;
    if (need <= ws_size){ C = cands[i]; break; }
  }
  size_t mo = zbase;
  auto malloc_ = [&](size_t bytes)->char*{ char* p = wsb + mo; mo = (mo + bytes + 255) & ~(size_t)255; return p; };
  float* m1c  = (float*)malloc_((size_t)C*32*784*4);
  float* m2b  = (float*)malloc_((size_t)C*16*12544*4);
  float* m3b  = (float*)malloc_((size_t)C*50176*4);

  // ---- upfront packs
  k_pack_frames<<<192, 256, 0, stream>>>(frames, XT);
  k_pack_wseq<<<4096, 256, 0, stream>>>(w_ih, w_hh, wseq);
  k_pack_dseq<<<3264, 256, 0, stream>>>(d1_w, actor_w, dseq);
  k_hfcT<<<4096, 256, 0, stream>>>(hfc_w, hfcT);
  k_misc<<<758, 256, 0, stream>>>(b_ih, b_hh, d1_b, actor_b, emb_w, h0, c0,
                                  dconv3_w, dconv2_w, dconv1_w,
                                  bias_g, bias_da, embT, hb, c_ws, Wt3, Wt2, Wt1);
  k_eb<<<290, 256, 0, stream>>>(enc, hfc_b, eb);

  // ---- upfront GEMMs (vis encoder chain + encH)
  gemm64<1,1><<<dim3(192,4), 256, 0, stream>>>(XT, 512, conv1_w, 512, Y1, 256, 12288, 256, 512, nullptr, conv1_b, bn1_g, bn1_b);
  gemm64<1,1><<<dim3(192,1), 256, 0, stream>>>(Y1, 256, conv2_w, 256, Y2, 64, 12288, 64, 256, nullptr, conv2_b, bn2_g, bn2_b);
  k_vis_in<<<192, 256, 0, stream>>>(Y2, vis_in);
  // fc: MT=12, NT=157 (n-major clustering: B=fc_w 31.4MB dominates)
  gemm16x<1,1><<<12*157, 64, 0, stream>>>(vis_in, 3136, fc_w, 3136, vis, 2500, 192, 2500, 3136, fc_b, 12, 157);
  k_xin<<<192, 256, 0, stream>>>(vis, gcn, xin2);
  // encH: MT=73, NT=64 (m-major clustering: A=enc 4.75MB dominates)
  gemm16x<0,0><<<73*64, 64, 0, stream>>>(enc, 1024, hfcT, 1024, encH, 1024, 1160, 1024, 1024, nullptr, 73, 64);

  // ---- pre-GEMMs for the (vis|gcn) columns, 2 chunks each (wchunk aliases XT, now dead)
  for (int c=0;c<2;c++){
    k_pack_wvg<<<2048, 256, 0, stream>>>(w_ih, wchunk, c*2048);
    gemm16x<0,1><<<12*128, 64, 0, stream>>>(xin2, 3072, wchunk, 3072, gates_pre + c*2048, 4096,
                                            192, 2048, 3072, bias_g + c*2048, 12, 128);
  }
  for (int c=0;c<2;c++){
    k_pack_dvg<<<1632, 256, 0, stream>>>(d1_w, actor_w, wchunk, c*1632);
    gemm16x<0,1><<<12*102, 64, 0, stream>>>(xin2, 3072, wchunk, 3072, d1a_pre + c*1632, 3264,
                                            192, 1632, 3072, bias_da + c*1632, 12, 102);
  }

  // ---- sequential loop
  for (int t=0; t<=24; t++){
    float* hcur = hb + (t&1)*8192;
    float* hnew = hb + ((t+1)&1)*8192;
    p1_scores_action<<<80, 256, 0, stream>>>(encH, eb, hcur, c_ws, scores_raw, d1a_out, embT,
                                             out_act, cmv, cmi, out_h, out_c, xb1, t);
    if (t == 24) break;
    p2_softmax_weighted<<<64, 256, 0, stream>>>(scores_raw, enc, weighted, e_cur, cmv, cmi, emb_w, go,
                                                out_attn, xb1, xb2, t);
    p3m<<<256, 64, 0, stream>>>(wseq, xb1, gates4);
    p3l<<<32, 256, 0, stream>>>(gates4, gates_pre, hnew, c_ws, xb2, t);
    p4m<<<204, 64, 0, stream>>>(dseq, xb2, d1a_pre, d1a_out, t);
  }

  // ---- mask decode (192/C chunks of C bt) — overwrites the out-scratch arena, reads only d1a_out (ws)
  for (int btbase=0; btbase<192; btbase+=C){
    md3_deconv<<<dim3(C,2,13), 256, 0, stream>>>(d1a_out, btbase, m1c, Wt3, dconv3_b, bnm2_g, bnm2_b);
    md2_deconv<<<dim3(C,196), 256, 0, stream>>>(m1c, m2b, Wt2, dconv2_b, bnm1_g, bnm1_b);
    md1_direct<<<dim3(C,49), 256, 0, stream>>>(m2b, m3b, dconv1_w, dconv1_b);
    k_resize<<<dim3(C,352), 256, 0, stream>>>(m3b, out_mask, btbase);
  }
}

// Round 5
// 2925.158 us; speedup vs baseline: 2.0509x; 1.0725x over previous
//
#include <hip/hip_runtime.h>
#include <cstdint>
#include <cstddef>

#define DEV __device__ __forceinline__
typedef short bf16x8 __attribute__((ext_vector_type(8)));
typedef float fl4 __attribute__((ext_vector_type(4)));
typedef float f32x4 __attribute__((ext_vector_type(4)));
typedef unsigned short u16;

#define BN_INV 0.9999950000375f

DEV float b2f(u16 u){ return __uint_as_float(((unsigned)u)<<16); }
DEV u16 f2b(float f){ unsigned u = __float_as_uint(f); unsigned r = (u + 0x7FFFu + ((u>>16)&1u))>>16; return (u16)r; }

DEV bf16x8 load8(const u16* p){ return *(const bf16x8*)p; }
DEV bf16x8 load8(const float* p){
  fl4 a = *(const fl4*)p; fl4 b = *(const fl4*)(p+4);
  bf16x8 r;
  r[0]=(short)f2b(a[0]); r[1]=(short)f2b(a[1]); r[2]=(short)f2b(a[2]); r[3]=(short)f2b(a[3]);
  r[4]=(short)f2b(b[0]); r[5]=(short)f2b(b[1]); r[6]=(short)f2b(b[2]); r[7]=(short)f2b(b[3]);
  return r;
}

// ---------------------------------------------------------------- pack kernels

// frames [192][512][49] f32 -> XT [192*64][512] bf16 (rows p>=49 zero)
__global__ __launch_bounds__(256) void k_pack_frames(const float* __restrict__ fr, u16* __restrict__ XT){
  int bt = blockIdx.x, tid = threadIdx.x;
  for (int e=0;e<128;e++){
    int flat = e*256 + tid;           // < 32768
    int p = flat>>9, c = flat&511;
    u16 v = 0;
    if (p < 49) v = f2b(fr[((size_t)bt*512 + c)*49 + p]);
    XT[((size_t)bt*64 + p)*512 + c] = v;
  }
}

// wseq [4096][2176] bf16 = [w_hh | w_ih cols 2500:3652]
__global__ __launch_bounds__(256) void k_pack_wseq(const float* __restrict__ w_ih, const float* __restrict__ w_hh,
                                                   u16* __restrict__ wseq){
  int r = blockIdx.x, tid = threadIdx.x;
  const float* wr = w_ih + (size_t)r*4164;
  for (int j=tid;j<2176;j+=256){
    float v = (j < 1024) ? w_hh[(size_t)r*1024 + j] : wr[2500 + (j-1024)];
    wseq[(size_t)r*2176 + j] = f2b(v);
  }
}

// dseq [3264][2176] bf16 = [dw cols 0:1024 | dw cols 3524:4676]  (rows 0:3136 d1_w, then actor_w)
__global__ __launch_bounds__(256) void k_pack_dseq(const float* __restrict__ d1_w, const float* __restrict__ actor_w,
                                                   u16* __restrict__ dseq){
  int r = blockIdx.x, tid = threadIdx.x;
  const float* wr = (r < 3136) ? (d1_w + (size_t)r*5188) : (actor_w + (size_t)(r-3136)*5188);
  for (int j=tid;j<2176;j+=256){
    float v = (j < 1024) ? wr[j] : wr[3524 + (j-1024)];
    dseq[(size_t)r*2176 + j] = f2b(v);
  }
}

// fcw [2500][3136] f32 -> bf16 (same f2b as load8(float*), so GEMM operands bitwise identical)
__global__ __launch_bounds__(256) void k_pack_fcw(const float* __restrict__ fc_w, u16* __restrict__ fcwB){
  int r = blockIdx.x, tid = threadIdx.x;
  const float* wr = fc_w + (size_t)r*3136;
  u16* dst = fcwB + (size_t)r*3136;
  for (int j=tid;j<3136;j+=256) dst[j] = f2b(wr[j]);
}

// wvg chunk [2048][3072] bf16 = [w_ih cols 0:2500 | w_ih cols 3652:4164 | 0]
__global__ __launch_bounds__(256) void k_pack_wvg(const float* __restrict__ w_ih, u16* __restrict__ wvg, int rbase){
  int r = rbase + blockIdx.x, tid = threadIdx.x;
  const float* wr = w_ih + (size_t)r*4164;
  u16* dst = wvg + (size_t)blockIdx.x*3072;
  for (int j=tid;j<3072;j+=256){
    float v = 0.f;
    if (j < 2500) v = wr[j];
    else if (j < 3012) v = wr[3652 + (j-2500)];
    dst[j] = f2b(v);
  }
}

// dvg chunk [1632][3072] bf16 = [dw cols 1024:3524 | dw cols 4676:5188 | 0]
__global__ __launch_bounds__(256) void k_pack_dvg(const float* __restrict__ d1_w, const float* __restrict__ actor_w,
                                                  u16* __restrict__ dvg, int rbase){
  int r = rbase + blockIdx.x, tid = threadIdx.x;
  const float* wr = (r < 3136) ? (d1_w + (size_t)r*5188) : (actor_w + (size_t)(r-3136)*5188);
  u16* dst = dvg + (size_t)blockIdx.x*3072;
  for (int j=tid;j<3072;j+=256){
    float v = 0.f;
    if (j < 2500) v = wr[1024 + j];
    else if (j < 3012) v = wr[4676 + (j-2500)];
    dst[j] = f2b(v);
  }
}

__global__ __launch_bounds__(256) void k_hfcT(const float* __restrict__ hfc_w, u16* __restrict__ hfcT){
  int idx = blockIdx.x*256 + threadIdx.x;   // 1M
  int k = idx>>10, o = idx&1023;
  hfcT[idx] = f2b(hfc_w[o*1024 + k]);
}

DEV u16 wt_map(const float* w, int n, int k, int CIN, int COUT){
  int o = n % COUT; int cls = n / COUT;
  if (cls >= 4) return 0;
  int py = cls>>1, px = cls&1;
  int i = k/9; int dd = k - i*9; int dy = dd/3, dx = dd - dy*3;
  if (i >= CIN) return 0;
  int ky = (py==0) ? (dy==0 ? 3 : (dy==1 ? 1 : -1)) : (dy==1 ? 2 : (dy==2 ? 0 : -1));
  int kx = (px==0) ? (dx==0 ? 3 : (dx==1 ? 1 : -1)) : (dx==1 ? 2 : (dx==2 ? 0 : -1));
  if (ky < 0 || kx < 0) return 0;
  return f2b(w[((i*COUT + o)*4 + ky)*4 + kx]);
}

__global__ __launch_bounds__(256) void k_misc(
  const float* b_ih, const float* b_hh, const float* d1_b, const float* actor_b,
  const float* emb_w, const float* h0, const float* c0,
  const float* dw3, const float* dw2, const float* dw1,
  float* bias_g, float* bias_da, u16* embT, float* hb0, float* cws,
  u16* Wt3, u16* Wt2, u16* Wt1)
{
  int blk = blockIdx.x, tid = threadIdx.x;
  if (blk < 16){ int i = blk*256+tid; if (i<4096) bias_g[i] = b_ih[i] + b_hh[i]; }
  else if (blk < 29){ int i = (blk-16)*256+tid; if (i<3264) bias_da[i] = (i<3136)? d1_b[i] : actor_b[i-3136]; }
  else if (blk < 541){ int i = (blk-29)*256+tid; int j = i>>10, v = i&1023; embT[i] = f2b(emb_w[v*128 + j]); }
  else if (blk < 573){ int i = (blk-541)*256+tid; if (i<8192){ hb0[i] = h0[i]; cws[i] = c0[i]; } }
  else if (blk < 574){ for (int i=tid;i<2560;i+=256){ int n=i/160, k=i-n*160; Wt1[i] = wt_map(dw1,n,k,16,1); } }
  else if (blk < 590){ for (int i=(blk-574)*256+tid; i<18432; i+=16*256){ int n=i/288, k=i-n*288; Wt2[i] = wt_map(dw2,n,k,32,16); } }
  else { for (int i=(blk-590)*256+tid; i<73728; i+=168*256){ int n=i/576, k=i-n*576; Wt3[i] = wt_map(dw3,n,k,64,32); } }
}

__global__ __launch_bounds__(256) void k_eb(const float* __restrict__ enc, const float* __restrict__ hfc_b, float* __restrict__ eb){
  int li = blockIdx.x*4 + (threadIdx.x>>6);
  int lane = threadIdx.x & 63;
  if (li >= 1160) return;
  const float* ep = enc + (size_t)li*1024;
  float a = 0.f;
  for (int k=lane;k<1024;k+=64) a += ep[k]*hfc_b[k];
  #pragma unroll
  for (int off=32; off; off>>=1) a += __shfl_xor(a, off);
  if (lane == 0) eb[li] = a;
}

// Y2 [192*64][64] bf16 -> vis_in [192][3136] bf16 (c*49+p ordering)
__global__ __launch_bounds__(256) void k_vis_in(const u16* __restrict__ Y2, u16* __restrict__ vis_in){
  int bt = blockIdx.x, tid = threadIdx.x;
  for (int f=tid; f<3136; f+=256){
    int c = f/49, p = f - c*49;
    vis_in[(size_t)bt*3136 + f] = Y2[((size_t)bt*64 + p)*64 + c];
  }
}

// xin2 [192][3072] bf16 = [vis 2500 | gcn 512 | 0]
__global__ __launch_bounds__(256) void k_xin(const u16* __restrict__ vis, const float* __restrict__ gcn, u16* __restrict__ xin2){
  int bt = blockIdx.x, tid = threadIdx.x, b = bt/24;
  for (int j=tid;j<3072;j+=256){
    u16 v = 0;
    if (j < 2500) v = vis[(size_t)bt*2500 + j];
    else if (j < 3012) v = f2b(gcn[b*512 + (j-2500)]);
    xin2[(size_t)bt*3072 + j] = v;
  }
}

// ---------------------------------------------------------------- generic MFMA GEMM (C[M,N] = A[M,K] @ B[N,K]^T)
// 64x64-tile version (used for the conv chain); k-slices of 32, increasing.
template<int OUTB, int ACT, typename TA, typename TB>
__global__ __launch_bounds__(256) void gemm64(
  const TA* __restrict__ A, int lda, const TB* __restrict__ Bm, int ldb,
  void* __restrict__ Cv, int ldc, int M, int N, int K,
  const float* __restrict__ bias, const float* __restrict__ cb, const float* __restrict__ gg, const float* __restrict__ bb)
{
  __shared__ u16 sA[64*72];
  __shared__ u16 sB[64*72];
  int tid = threadIdx.x, lane = tid & 63, w = tid >> 6;
  int wm = w & 1, wn = w >> 1;
  int m0 = blockIdx.x*64, n0 = blockIdx.y*64;
  f32x4 acc[2][2];
  #pragma unroll
  for (int a=0;a<2;a++)
    #pragma unroll
    for (int b=0;b<2;b++){ acc[a][b][0]=0;acc[a][b][1]=0;acc[a][b][2]=0;acc[a][b][3]=0; }

  for (int k0=0;k0<K;k0+=64){
    #pragma unroll
    for (int j=0;j<2;j++){
      int c = tid + 256*j; int row = c>>3; int col = (c&7)*8;
      bf16x8 va = {0,0,0,0,0,0,0,0};
      int gm = m0 + row;
      if (gm < M) va = load8(A + (size_t)gm*lda + k0 + col);
      *(bf16x8*)(&sA[row*72 + col]) = va;
      bf16x8 vb = {0,0,0,0,0,0,0,0};
      int gn = n0 + row;
      if (gn < N) vb = load8(Bm + (size_t)gn*ldb + k0 + col);
      *(bf16x8*)(&sB[row*72 + col]) = vb;
    }
    __syncthreads();
    #pragma unroll
    for (int kk=0;kk<2;kk++){
      bf16x8 af[2], bfv[2];
      #pragma unroll
      for (int tm=0;tm<2;tm++) af[tm]  = *(const bf16x8*)(&sA[(wm*32+tm*16+(lane&15))*72 + kk*32 + (lane>>4)*8]);
      #pragma unroll
      for (int tn=0;tn<2;tn++) bfv[tn] = *(const bf16x8*)(&sB[(wn*32+tn*16+(lane&15))*72 + kk*32 + (lane>>4)*8]);
      #pragma unroll
      for (int tm=0;tm<2;tm++)
        #pragma unroll
        for (int tn=0;tn<2;tn++)
          acc[tm][tn] = __builtin_amdgcn_mfma_f32_16x16x32_bf16(af[tm], bfv[tn], acc[tm][tn], 0,0,0);
    }
    __syncthreads();
  }
  int ml = (lane>>4)*4, nl = lane&15;
  #pragma unroll
  for (int tm=0;tm<2;tm++)
    #pragma unroll
    for (int tn=0;tn<2;tn++)
      #pragma unroll
      for (int r=0;r<4;r++){
        int gm = m0 + wm*32 + tm*16 + ml + r;
        int gn = n0 + wn*32 + tn*16 + nl;
        if (gm < M && gn < N){
          float v = acc[tm][tn][r];
          if (ACT == 0){ if (bias) v += bias[gn]; }
          else { v = (v + cb[gn])*BN_INV*gg[gn] + bb[gn]; v = fmaxf(v, 0.f); }
          if (OUTB) ((u16*)Cv)[(size_t)gm*ldc + gn] = f2b(v);
          else      ((float*)Cv)[(size_t)gm*ldc + gn] = v;
        }
      }
}

// 16x16-tile 1-wave GEMM with bijective XCD-swizzle.  Bitwise-identical per-output
// accumulation chain (increasing k-slices of 32, same f2b operand conversion).
template<int OUTB, int NMAJOR, typename TA, typename TB>
__global__ __launch_bounds__(64) void gemm16x(
  const TA* __restrict__ A, int lda, const TB* __restrict__ Bm, int ldb,
  void* __restrict__ Cv, int ldc, int M, int N, int K, const float* __restrict__ bias,
  int MT, int NT)
{
  int nb = gridDim.x;
  int orig = blockIdx.x;
  int q = nb >> 3, r = nb & 7;
  int xcd = orig & 7, j = orig >> 3;
  int wg = (xcd < r ? xcd*(q+1) : r*(q+1) + (xcd-r)*q) + j;
  int bx, by;
  if (NMAJOR){ bx = wg % MT; by = wg / MT; }
  else       { by = wg % NT; bx = wg / NT; }
  int lane = threadIdx.x;
  int m0 = bx*16, n0 = by*16;
  int gm = m0 + (lane&15); if (gm > M-1) gm = M-1;   // clamp: rows >=M never stored
  int gn = n0 + (lane&15); if (gn > N-1) gn = N-1;   // clamp: cols >=N never stored
  const TA* ap = A  + (size_t)gm*lda + ((lane>>4)*8);
  const TB* bp = Bm + (size_t)gn*ldb + ((lane>>4)*8);
  f32x4 acc = {0,0,0,0};
  #pragma unroll 8
  for (int ks=0; ks<K; ks+=32){
    bf16x8 a = load8(ap + ks);
    bf16x8 b = load8(bp + ks);
    acc = __builtin_amdgcn_mfma_f32_16x16x32_bf16(a, b, acc, 0,0,0);
  }
  int nn = n0 + (lane&15);
  if (nn >= N) return;
  #pragma unroll
  for (int r2=0;r2<4;r2++){
    int mm = m0 + (lane>>4)*4 + r2;
    if (mm < M){
      float v = acc[r2];
      if (bias) v += bias[nn];
      if (OUTB) ((u16*)Cv)[(size_t)mm*ldc + nn] = f2b(v);
      else      ((float*)Cv)[(size_t)mm*ldc + nn] = v;
    }
  }
}

// ---------------------------------------------------------------- per-step kernels

// P1: scores (blocks 0-39, XCD-pinned: b = blk&7 so encH[b] stays in one XCD's L2
// across steps) + action/argmax of t-1 (40-71) + h-pack / h,c output (72-79)
__global__ __launch_bounds__(256) void p1_scores_action(
  const float* __restrict__ encH, const float* __restrict__ eb,
  const float* __restrict__ hcur, const float* __restrict__ cws,
  float* __restrict__ scores, const float* __restrict__ d1a_out,
  const u16* __restrict__ embT, float* __restrict__ out_act,
  float* __restrict__ cmv, int* __restrict__ cmi,
  float* __restrict__ out_h, float* __restrict__ out_c,
  u16* __restrict__ xb1, int t)
{
  __shared__ float shf[1024];
  __shared__ int shi[256];
  int blk = blockIdx.x, tid = threadIdx.x;
  if (blk < 40){
    if (t == 24) return;
    int b = blk & 7, lc = blk >> 3;     // XCD-pinned relabel (bijective over [0,40))
    #pragma unroll
    for (int e=0;e<4;e++) shf[tid + 256*e] = hcur[b*1024 + tid + 256*e];
    __syncthreads();
    int w = tid>>6, lane = tid&63;
    for (int i=w;i<29;i+=4){
      int l = lc*29 + i;
      const float* ep = encH + (size_t)(b*145+l)*1024;
      float a = 0.f;
      for (int k=lane;k<1024;k+=64) a += ep[k]*shf[k];
      #pragma unroll
      for (int off=32; off; off>>=1) a += __shfl_xor(a, off);
      if (lane == 0) scores[b*145+l] = a + eb[b*145+l];
    }
  } else if (blk < 72){
    if (t == 0) return;
    int idx = blk-40; int b = idx>>2, vc = idx&3;
    if (tid < 128) shf[tid] = d1a_out[(size_t)(b*24 + t-1)*3264 + 3136 + tid];
    __syncthreads();
    int v = vc*256 + tid;
    float a = 0.f;
    for (int j=0;j<128;j++) a += shf[j]*b2f(embT[j*1024 + v]);
    out_act[(size_t)(b*24 + t-1)*1024 + v] = a;
    shf[256+tid] = a; shi[tid] = v;
    __syncthreads();
    for (int s=128; s; s>>=1){
      if (tid < s){
        float o = shf[256+tid+s]; int oi = shi[tid+s];
        float c = shf[256+tid];   int ci = shi[tid];
        if (o > c || (o == c && oi < ci)){ shf[256+tid] = o; shi[tid] = oi; }
      }
      __syncthreads();
    }
    if (tid == 0){ cmv[b*4+vc] = shf[256]; cmi[b*4+vc] = shi[0]; }
  } else {
    int b = blk-72;
    if (t == 24){
      #pragma unroll
      for (int e=0;e<4;e++){
        int k = tid + 256*e;
        out_h[b*1024+k] = hcur[b*1024+k];
        out_c[b*1024+k] = cws[b*1024+k];
      }
    } else {
      #pragma unroll
      for (int e=0;e<4;e++){
        int k = tid + 256*e;
        xb1[b*2176 + k] = f2b(hcur[b*1024+k]);
      }
    }
  }
}

// P2: softmax + weighted + attn-out + e selection; XCD-pinned b = blk&7.
__global__ __launch_bounds__(256) void p2_softmax_weighted(
  const float* __restrict__ scores, const float* __restrict__ enc,
  float* __restrict__ wgt, float* __restrict__ ecur,
  const float* __restrict__ cmv, const int* __restrict__ cmi,
  const float* __restrict__ emb_w, const float* __restrict__ go,
  float* __restrict__ out_attn, u16* __restrict__ xb1, u16* __restrict__ xb2, int t)
{
  int b = blockIdx.x & 7, dc = blockIdx.x >> 3, tid = threadIdx.x;  // pinned relabel
  __shared__ float s[145];
  __shared__ float mxs, invs;
  if (tid < 145) s[tid] = scores[b*145+tid];
  __syncthreads();
  if (tid < 64){
    float m = -1e30f;
    for (int i=tid;i<145;i+=64) m = fmaxf(m, s[i]);
    #pragma unroll
    for (int off=32; off; off>>=1) m = fmaxf(m, __shfl_xor(m, off));
    if (tid == 0) mxs = m;
  }
  __syncthreads();
  if (tid < 145) s[tid] = expf(s[tid]-mxs);
  __syncthreads();
  if (tid < 64){
    float sm = 0.f;
    for (int i=tid;i<145;i+=64) sm += s[i];
    #pragma unroll
    for (int off=32; off; off>>=1) sm += __shfl_xor(sm, off);
    if (tid == 0) invs = 1.f/sm;
  }
  __syncthreads();
  float inv = invs;
  if (tid < 128){
    int d = dc*128 + tid;
    float a = 0.f;
    for (int l=0;l<145;l++) a += s[l]*enc[(size_t)(b*145+l)*1024 + d];
    float wv = a*inv;
    wgt[b*1024+d] = wv;
    u16 wb = f2b(wv);
    xb1[b*2176 + 1024 + d] = wb;
    xb2[b*2176 + 1024 + d] = wb;
  } else {
    int i = tid-128;
    if (dc == 0){
      if (i < 145) out_attn[(size_t)(b*24+t)*145 + i] = s[i]*inv;
      int l2 = i + 128;
      if (l2 < 145) out_attn[(size_t)(b*24+t)*145 + l2] = s[l2]*inv;
    } else if (dc == 1){
      float ev;
      if (t == 0) ev = go[i];
      else {
        float bv = cmv[b*4]; int bi = cmi[b*4];
        #pragma unroll
        for (int c=1;c<4;c++){
          float v2 = cmv[b*4+c]; int i2 = cmi[b*4+c];
          if (v2 > bv || (v2 == bv && i2 < bi)){ bv = v2; bi = i2; }
        }
        ev = emb_w[bi*128 + i];
      }
      ecur[b*128+i] = ev;
      u16 eb16 = f2b(ev);
      xb1[b*2176 + 2048 + i] = eb16;
      xb2[b*2176 + 2048 + i] = eb16;
    }
  }
}

// P3m: gates GEMM, one wave per 16 output cols; bitwise-identical 68-MFMA chain.
// XCD-swizzled (256 blocks, q=32): XCD k owns wseq rows [k*512, k*512+512) -> 2.2MB
// slice stays L2-resident across the 24 steps.
__global__ __launch_bounds__(64) void p3m(
  const u16* __restrict__ wseq, const u16* __restrict__ xb, float* __restrict__ gates4)
{
  int orig = blockIdx.x;
  int blk = (orig & 7)*32 + (orig >> 3);   // bijective, 256 = 8*32
  int lane = threadIdx.x;
  int n = blk*16 + (lane & 15);
  const u16* bp = wseq + (size_t)n*2176 + ((lane>>4)*8);
  const u16* ap = xb + (lane&7)*2176 + ((lane>>4)*8);
  f32x4 acc = {0,0,0,0};
  #pragma unroll 8
  for (int kk=0;kk<68;kk++){
    bf16x8 a = *(const bf16x8*)(ap + kk*32);
    bf16x8 b = *(const bf16x8*)(bp + kk*32);
    acc = __builtin_amdgcn_mfma_f32_16x16x32_bf16(a, b, acc, 0,0,0);
  }
  #pragma unroll
  for (int r=0;r<4;r++){
    int m = (lane>>4)*4 + r;
    if (m < 8) gates4[(size_t)m*4096 + n] = acc[r];
  }
}

// P3l: LSTM elementwise; packs hnew into xb2.
__global__ __launch_bounds__(256) void p3l(
  const float* __restrict__ gates4, const float* __restrict__ gpre,
  float* __restrict__ hnew, float* __restrict__ cws, u16* __restrict__ xb2, int t)
{
  int idx = blockIdx.x*256 + threadIdx.x;   // 8192
  int b = idx>>10, J = idx&1023;
  const float* gp = gpre + (size_t)(b*24+t)*4096;
  const float* gb = gates4 + (size_t)b*4096;
  float iv = gb[J]      + gp[J];
  float fv = gb[1024+J] + gp[1024+J];
  float gv = gb[2048+J] + gp[2048+J];
  float ov = gb[3072+J] + gp[3072+J];
  float ig = 1.f/(1.f+expf(-iv));
  float fg = 1.f/(1.f+expf(-fv));
  float gt = tanhf(gv);
  float og = 1.f/(1.f+expf(-ov));
  float cn = fg*cws[idx] + ig*gt;
  cws[idx] = cn;
  float hv = og*tanhf(cn);
  hnew[idx] = hv;
  xb2[b*2176 + J] = f2b(hv);
}

// P4m: d1+actor GEMM, one wave per 16 output cols; XCD-swizzled (204 blocks, q=25 r=4)
// so each XCD's ~1.8MB dseq slice stays L2-resident across steps.
__global__ __launch_bounds__(64) void p4m(
  const u16* __restrict__ dseq, const u16* __restrict__ xb2,
  const float* __restrict__ dpre, float* __restrict__ dout, int t)
{
  int orig = blockIdx.x;                   // 204 blocks
  int xcd = orig & 7, j = orig >> 3;
  int blk = (xcd < 4 ? xcd*26 : 104 + (xcd-4)*25) + j;
  int lane = threadIdx.x;
  int R = blk*16 + (lane & 15);
  const u16* bp = dseq + (size_t)R*2176 + ((lane>>4)*8);
  const u16* ap = xb2 + (lane&7)*2176 + ((lane>>4)*8);
  f32x4 acc = {0,0,0,0};
  #pragma unroll 8
  for (int kk=0;kk<68;kk++){
    bf16x8 a = *(const bf16x8*)(ap + kk*32);
    bf16x8 b = *(const bf16x8*)(bp + kk*32);
    acc = __builtin_amdgcn_mfma_f32_16x16x32_bf16(a, b, acc, 0,0,0);
  }
  #pragma unroll
  for (int r=0;r<4;r++){
    int m = (lane>>4)*4 + r;
    if (m < 8){
      size_t row = (size_t)(m*24+t)*3264;
      dout[row + R] = acc[r] + dpre[row + R];
    }
  }
}

// ---------------------------------------------------------------- mask decode

// stage for deconv3: read straight from d1a_out (fold up2 7->14 + relu).
DEV void stage_tile3(u16* sAt, const float* __restrict__ d1a_bt, int p0, int tid){
  int m = tid & 15;
  int p = p0 + m;
  int u = p / 14, v = p - u*14;
  bool pv = p < 196;
  for (int k = tid>>4; k < 576; k += 16){
    float val = 0.f;
    if (pv){
      int i = k/9; int dd = k - i*9; int dy = dd/3, dx = dd - dy*3;
      int uy = u + dy - 1, vx = v + dx - 1;
      if (uy >= 0 && uy < 14 && vx >= 0 && vx < 14)
        val = fmaxf(d1a_bt[i*49 + (uy>>1)*7 + (vx>>1)], 0.f);
    }
    sAt[m*584 + k] = f2b(val);
  }
}

// stage for deconv2: read m1c [32][28][28] (fold up2 28->56).
DEV void stage_tile2(u16* sAt, const float* __restrict__ m1c_bt, int p0, int tid){
  int m = tid & 15;
  int p = p0 + m;
  int u = p / 56, v = p - u*56;
  bool pv = p < 3136;
  for (int k = tid>>4; k < 288; k += 16){
    float val = 0.f;
    if (pv){
      int i = k/9; int dd = k - i*9; int dy = dd/3, dx = dd - dy*3;
      int uy = u + dy - 1, vx = v + dx - 1;
      if (uy >= 0 && uy < 56 && vx >= 0 && vx < 56)
        val = m1c_bt[i*784 + (uy>>1)*28 + (vx>>1)];
    }
    sAt[m*296 + k] = f2b(val);
  }
}

// deconv3 (64->32, in-grid 14) -> m1c [32][28][28]; grid (C, 2, 13)
__global__ __launch_bounds__(256) void md3_deconv(const float* __restrict__ d1a_out, int btbase, float* __restrict__ m1c,
  const u16* __restrict__ Wt3, const float* __restrict__ b3, const float* __restrict__ g3, const float* __restrict__ bb3)
{
  __shared__ u16 sAt[16*584];
  int tid = threadIdx.x, lane = tid&63, w = tid>>6;
  int cb = blockIdx.x;
  const float* in_bt = d1a_out + (size_t)(btbase+cb)*3264;
  float* out_bt = m1c + (size_t)cb*32*784;
  int nt = blockIdx.y*4 + w;
  bf16x8 wc[18];
  #pragma unroll
  for (int ks=0;ks<18;ks++) wc[ks] = *(const bf16x8*)(Wt3 + (size_t)(nt*16 + (lane&15))*576 + ks*32 + (lane>>4)*8);
  int cls = nt>>1; int o = (nt&1)*16 + (lane&15);
  int py = cls>>1, px = cls&1;
  float cbv = b3[o], gv = g3[o], bbv = bb3[o];
  int mt = blockIdx.z;
  stage_tile3(sAt, in_bt, mt*16, tid);
  __syncthreads();
  f32x4 acc = {0,0,0,0};
  #pragma unroll
  for (int ks=0;ks<18;ks++){
    bf16x8 a = *(const bf16x8*)(&sAt[(lane&15)*584 + ks*32 + (lane>>4)*8]);
    acc = __builtin_amdgcn_mfma_f32_16x16x32_bf16(a, wc[ks], acc, 0,0,0);
  }
  #pragma unroll
  for (int r=0;r<4;r++){
    int p = mt*16 + (lane>>4)*4 + r;
    if (p < 196){
      int u = p/14, v = p - (p/14)*14;
      float vv = fmaxf((acc[r] + cbv)*BN_INV*gv + bbv, 0.f);
      out_bt[((size_t)o*28 + (2*u+py))*28 + (2*v+px)] = vv;
    }
  }
}

// deconv2 (32->16, in-grid 56 via folded up2 of m1c) -> m2 [16][112][112]; grid (C, 196)
__global__ __launch_bounds__(256) void md2_deconv(const float* __restrict__ m1c, float* __restrict__ m2,
  const u16* __restrict__ Wt2, const float* __restrict__ b2, const float* __restrict__ g2, const float* __restrict__ bb2)
{
  __shared__ u16 sAt[16*296];
  int tid = threadIdx.x, lane = tid&63, w = tid>>6;
  int cb = blockIdx.x;
  const float* in_bt = m1c + (size_t)cb*32*784;
  float* out_bt = m2 + (size_t)cb*16*12544;
  int nt = w;
  bf16x8 wc[9];
  #pragma unroll
  for (int ks=0;ks<9;ks++) wc[ks] = *(const bf16x8*)(Wt2 + (size_t)(nt*16 + (lane&15))*288 + ks*32 + (lane>>4)*8);
  int cls = nt; int o = lane&15;
  int py = cls>>1, px = cls&1;
  float cbv = b2[o], gv = g2[o], bbv = bb2[o];
  int mt = blockIdx.y;
  stage_tile2(sAt, in_bt, mt*16, tid);
  __syncthreads();
  f32x4 acc = {0,0,0,0};
  #pragma unroll
  for (int ks=0;ks<9;ks++){
    bf16x8 a = *(const bf16x8*)(&sAt[(lane&15)*296 + ks*32 + (lane>>4)*8]);
    acc = __builtin_amdgcn_mfma_f32_16x16x32_bf16(a, wc[ks], acc, 0,0,0);
  }
  #pragma unroll
  for (int r=0;r<4;r++){
    int p = mt*16 + (lane>>4)*4 + r;
    if (p < 3136){
      int u = p/56, v = p - u*56;
      float vv = fmaxf((acc[r] + cbv)*BN_INV*gv + bbv, 0.f);
      out_bt[((size_t)o*112 + (2*u+py))*112 + (2*v+px)] = vv;
    }
  }
}

// deconv1 (16->1, in-grid 112) -> m3 [224][224], direct fp32 VALU.
__global__ __launch_bounds__(256) void md1_direct(const float* __restrict__ m2, float* __restrict__ m3,
  const float* __restrict__ dw1, const float* __restrict__ b1)
{
  __shared__ float wl[256];               // dconv1_w: [i][ky][kx] = 16*4*4
  int tid = threadIdx.x;
  wl[tid] = dw1[tid];
  __syncthreads();
  int cb = blockIdx.x;
  const float* in_bt = m2 + (size_t)cb*16*12544;
  float* out_bt = m3 + (size_t)cb*50176;
  int idx = blockIdx.y*256 + tid;         // [0, 12544) : 224 rows x 56 quads
  int oy = idx/56, q = idx - oy*56;
  int ox0 = q*4;
  int iyA = (oy+1)>>1;  bool vA = iyA < 112;
  int iyB = iyA - 1;    bool vB = iyB >= 0;
  int kyA = (oy&1) ? 0 : 1;
  int kyB = kyA + 2;
  int xb = (ox0>>1) - 1;
  bool v0 = xb >= 0, v3 = (xb+3) < 112;
  int x0 = v0 ? xb : 0, x3 = v3 ? xb+3 : 111;
  float mA = vA ? 1.f : 0.f, mB = vB ? 1.f : 0.f;
  float mA0 = v0 ? mA : 0.f, mA3 = v3 ? mA : 0.f;
  float mB0 = v0 ? mB : 0.f, mB3 = v3 ? mB : 0.f;
  const float* rA = in_bt + (size_t)(vA ? iyA : 0)*112;
  const float* rB = in_bt + (size_t)(vB ? iyB : 0)*112;
  float acc0=0.f, acc1=0.f, acc2=0.f, acc3=0.f;
  #pragma unroll 4
  for (int i=0;i<16;i++){
    const float* cA = rA + i*12544;
    const float* cB = rB + i*12544;
    float a0 = cA[x0]*mA0, a1 = cA[xb+1]*mA, a2 = cA[xb+2]*mA, a3 = cA[x3]*mA3;
    float b0 = cB[x0]*mB0, b1v = cB[xb+1]*mB, b2 = cB[xb+2]*mB, b3 = cB[x3]*mB3;
    fl4 wA = *(const fl4*)(&wl[i*16 + kyA*4]);
    fl4 wB = *(const fl4*)(&wl[i*16 + kyB*4]);
    acc0 += a1*wA[1] + a0*wA[3] + b1v*wB[1] + b0*wB[3];
    acc1 += a2*wA[0] + a1*wA[2] + b2*wB[0] + b1v*wB[2];
    acc2 += a2*wA[1] + a1*wA[3] + b2*wB[1] + b1v*wB[3];
    acc3 += a3*wA[0] + a2*wA[2] + b3*wB[0] + b2*wB[2];
  }
  float bv = b1[0];
  fl4 o4 = {acc0+bv, acc1+bv, acc2+bv, acc3+bv};
  *(fl4*)(out_bt + (size_t)oy*224 + ox0) = o4;
}

__global__ __launch_bounds__(256) void k_resize(const float* __restrict__ m3, float* __restrict__ out_mask, int btbase){
  int cb = blockIdx.x;
  const float* in_bt = m3 + (size_t)cb*50176;
  int idx = blockIdx.y*256 + threadIdx.x;
  if (idx >= 90000) return;
  int oy = idx/300, ox = idx - oy*300;
  const float sc = 224.f/300.f;
  float sy = (oy+0.5f)*sc - 0.5f;
  float sx = (ox+0.5f)*sc - 0.5f;
  float fy = floorf(sy), fx = floorf(sx);
  float wy = sy-fy, wx = sx-fx;
  int y0 = (int)fy, x0 = (int)fx;
  int y0c = min(max(y0,0),223), y1c = min(max(y0+1,0),223);
  int x0c = min(max(x0,0),223), x1c = min(max(x0+1,0),223);
  float v00 = in_bt[y0c*224+x0c], v01 = in_bt[y0c*224+x1c];
  float v10 = in_bt[y1c*224+x0c], v11 = in_bt[y1c*224+x1c];
  float v = (1.f-wy)*((1.f-wx)*v00 + wx*v01) + wy*((1.f-wx)*v10 + wx*v11);
  out_mask[(size_t)(btbase+cb)*90000 + idx] = v;
}

// ---------------------------------------------------------------- host

extern "C" void kernel_launch(void* const* d_in, const int* in_sizes, int n_in,
                              void* d_out, int out_size, void* d_ws, size_t ws_size,
                              hipStream_t stream)
{
  const float* enc      = (const float*)d_in[0];
  const float* frames   = (const float*)d_in[1];
  const float* gcn      = (const float*)d_in[2];
  const float* h0       = (const float*)d_in[3];
  const float* c0       = (const float*)d_in[4];
  const float* conv1_w  = (const float*)d_in[5];
  const float* conv1_b  = (const float*)d_in[6];
  const float* bn1_g    = (const float*)d_in[7];
  const float* bn1_b    = (const float*)d_in[8];
  const float* conv2_w  = (const float*)d_in[9];
  const float* conv2_b  = (const float*)d_in[10];
  const float* bn2_g    = (const float*)d_in[11];
  const float* bn2_b    = (const float*)d_in[12];
  const float* fc_w     = (const float*)d_in[13];
  const float* fc_b     = (const float*)d_in[14];
  const float* hfc_w    = (const float*)d_in[15];
  const float* hfc_b    = (const float*)d_in[16];
  const float* w_ih     = (const float*)d_in[17];
  const float* w_hh     = (const float*)d_in[18];
  const float* b_ih     = (const float*)d_in[19];
  const float* b_hh     = (const float*)d_in[20];
  const float* go       = (const float*)d_in[21];
  const float* emb_w    = (const float*)d_in[22];
  const float* actor_w  = (const float*)d_in[23];
  const float* actor_b  = (const float*)d_in[24];
  const float* d1_w     = (const float*)d_in[25];
  const float* d1_b     = (const float*)d_in[26];
  const float* dconv3_w = (const float*)d_in[27];
  const float* dconv3_b = (const float*)d_in[28];
  const float* bnm2_g   = (const float*)d_in[29];
  const float* bnm2_b   = (const float*)d_in[30];
  const float* dconv2_w = (const float*)d_in[31];
  const float* dconv2_b = (const float*)d_in[32];
  const float* bnm1_g   = (const float*)d_in[33];
  const float* bnm1_b   = (const float*)d_in[34];
  const float* dconv1_w = (const float*)d_in[35];
  const float* dconv1_b = (const float*)d_in[36];
  (void)in_sizes; (void)n_in; (void)out_size;

  // ---- output layout (float element offsets)
  float* obase    = (float*)d_out;
  float* out_act  = obase;                // 196608
  float* out_mask = obase + 196608;       // 17280000 (69.12 MB — scratch arena until decode)
  float* out_attn = obase + 17476608;     // 27840
  float* out_h    = obase + 17504448;     // 8192
  float* out_c    = obase + 17512640;     // 8192

  // ---- big scratch arena = out_mask region, written only by the final decode phase
  char* ob = (char*)out_mask;
  size_t ooff = 0;
  auto oalloc = [&](size_t bytes)->char*{ char* p = ob + ooff; ooff = (ooff + bytes + 255) & ~(size_t)255; return p; };
  // live through the loop:
  u16*   wseq      = (u16*)  oalloc(4096ULL*2176*2);    // 17.8 MB
  u16*   dseq      = (u16*)  oalloc(3264ULL*2176*2);    // 14.2 MB
  float* encH      = (float*)oalloc(1160ULL*1024*4);    // 4.75 MB
  float* gates_pre = (float*)oalloc(192ULL*4096*4);     // 3.15 MB
  float* d1a_pre   = (float*)oalloc(192ULL*3264*4);     // 2.51 MB
  u16*   xin2      = (u16*)  oalloc(192ULL*3072*2);     // 1.18 MB (dead after pre-GEMMs)
  // transient conv-chain zone (dead before the loop starts):
  u16*   XT     = (u16*)oalloc(12288ULL*512*2);         // 12.6 MB
  u16*   Y1     = (u16*)oalloc(12288ULL*256*2);         // 6.3 MB
  u16*   Y2     = (u16*)oalloc(12288ULL*64*2);          // 1.6 MB
  u16*   vis_in = (u16*)oalloc(192ULL*3136*2);          // 1.2 MB
  u16*   vis    = (u16*)oalloc(192ULL*2500*2);          // 0.96 MB
  u16*   wchunk = XT;   // pre-GEMM weight chunk aliases XT (dead by then); 12.58MB <= 12.6MB
  u16*   fcwB   = XT;   // packed fc_w bf16: 2500*3136*2 = 15.68MB <= XT+Y1 (18.87MB); dead before wchunk use
  // total ~66.3 MB <= 69.12 MB

  // ---- ws: small persistent state + d1a_out + hfcT/decode-chunk alias zone
  char* wsb = (char*)d_ws;
  size_t off = 0;
  auto alloc = [&](size_t bytes)->char*{ char* p = wsb + off; off = (off + bytes + 255) & ~(size_t)255; return p; };
  float* d1a_out   = (float*)alloc(192ULL*3264*4);      // 2.5 MB, read by decode
  u16*   embT      = (u16*)  alloc(128ULL*1024*2);
  float* eb        = (float*)alloc(1160ULL*4);
  u16*   Wt3       = (u16*)  alloc(128ULL*576*2);
  u16*   Wt2       = (u16*)  alloc(64ULL*288*2);
  u16*   Wt1       = (u16*)  alloc(16ULL*160*2);
  float* hb        = (float*)alloc(2ULL*8192*4);
  float* c_ws      = (float*)alloc(8192ULL*4);
  float* e_cur     = (float*)alloc(8ULL*128*4);
  float* weighted  = (float*)alloc(8192ULL*4);
  float* scores_raw= (float*)alloc(8ULL*145*4);
  float* cmv       = (float*)alloc(32ULL*4);
  int*   cmi       = (int*)  alloc(32ULL*4);
  float* bias_g    = (float*)alloc(4096ULL*4);
  float* bias_da   = (float*)alloc(3264ULL*4);
  u16*   xb1       = (u16*)  alloc(8ULL*2176*2);        // packed [h|wgt|e] (hcur)
  u16*   xb2       = (u16*)  alloc(8ULL*2176*2);        // packed [h|wgt|e] (hnew)
  float* gates4    = (float*)alloc(8ULL*4096*4);        // per-step gates
  size_t zbase = off;
  u16*   hfcT = (u16*)alloc(1024ULL*1024*2);            // dead after encH gemm

  // decode chunk buffers alias hfcT zone; per-bt = m1c 100352 + m2 802816 + m3 200704 = 1103872 B
  const int cands[10] = {48,24,16,12,8,6,4,3,2,1};
  int C = 1;
  for (int i=0;i<10;i++){
    size_t need = zbase + (size_t)cands[i]*1103872ULL + 65536;
    if (need <= ws_size){ C = cands[i]; break; }
  }
  size_t mo = zbase;
  auto malloc_ = [&](size_t bytes)->char*{ char* p = wsb + mo; mo = (mo + bytes + 255) & ~(size_t)255; return p; };
  float* m1c  = (float*)malloc_((size_t)C*32*784*4);
  float* m2b  = (float*)malloc_((size_t)C*16*12544*4);
  float* m3b  = (float*)malloc_((size_t)C*50176*4);

  // ---- upfront packs
  k_pack_frames<<<192, 256, 0, stream>>>(frames, XT);
  k_pack_wseq<<<4096, 256, 0, stream>>>(w_ih, w_hh, wseq);
  k_pack_dseq<<<3264, 256, 0, stream>>>(d1_w, actor_w, dseq);
  k_hfcT<<<4096, 256, 0, stream>>>(hfc_w, hfcT);
  k_misc<<<758, 256, 0, stream>>>(b_ih, b_hh, d1_b, actor_b, emb_w, h0, c0,
                                  dconv3_w, dconv2_w, dconv1_w,
                                  bias_g, bias_da, embT, hb, c_ws, Wt3, Wt2, Wt1);
  k_eb<<<290, 256, 0, stream>>>(enc, hfc_b, eb);

  // ---- upfront GEMMs (vis encoder chain + encH)
  gemm64<1,1><<<dim3(192,4), 256, 0, stream>>>(XT, 512, conv1_w, 512, Y1, 256, 12288, 256, 512, nullptr, conv1_b, bn1_g, bn1_b);
  gemm64<1,1><<<dim3(192,1), 256, 0, stream>>>(Y1, 256, conv2_w, 256, Y2, 64, 12288, 64, 256, nullptr, conv2_b, bn2_g, bn2_b);
  k_vis_in<<<192, 256, 0, stream>>>(Y2, vis_in);
  // pack fc_w -> bf16 into XT+Y1 (both dead now); then fc with bf16 B
  k_pack_fcw<<<2500, 256, 0, stream>>>(fc_w, fcwB);
  gemm16x<1,1><<<12*157, 64, 0, stream>>>(vis_in, 3136, fcwB, 3136, vis, 2500, 192, 2500, 3136, fc_b, 12, 157);
  k_xin<<<192, 256, 0, stream>>>(vis, gcn, xin2);
  // encH: MT=73, NT=64 (m-major clustering: A=enc 4.75MB dominates)
  gemm16x<0,0><<<73*64, 64, 0, stream>>>(enc, 1024, hfcT, 1024, encH, 1024, 1160, 1024, 1024, nullptr, 73, 64);

  // ---- pre-GEMMs for the (vis|gcn) columns, 2 chunks each (wchunk aliases XT, fcwB dead)
  for (int c=0;c<2;c++){
    k_pack_wvg<<<2048, 256, 0, stream>>>(w_ih, wchunk, c*2048);
    gemm16x<0,1><<<12*128, 64, 0, stream>>>(xin2, 3072, wchunk, 3072, gates_pre + c*2048, 4096,
                                            192, 2048, 3072, bias_g + c*2048, 12, 128);
  }
  for (int c=0;c<2;c++){
    k_pack_dvg<<<1632, 256, 0, stream>>>(d1_w, actor_w, wchunk, c*1632);
    gemm16x<0,1><<<12*102, 64, 0, stream>>>(xin2, 3072, wchunk, 3072, d1a_pre + c*1632, 3264,
                                            192, 1632, 3072, bias_da + c*1632, 12, 102);
  }

  // ---- sequential loop
  for (int t=0; t<=24; t++){
    float* hcur = hb + (t&1)*8192;
    float* hnew = hb + ((t+1)&1)*8192;
    p1_scores_action<<<80, 256, 0, stream>>>(encH, eb, hcur, c_ws, scores_raw, d1a_out, embT,
                                             out_act, cmv, cmi, out_h, out_c, xb1, t);
    if (t == 24) break;
    p2_softmax_weighted<<<64, 256, 0, stream>>>(scores_raw, enc, weighted, e_cur, cmv, cmi, emb_w, go,
                                                out_attn, xb1, xb2, t);
    p3m<<<256, 64, 0, stream>>>(wseq, xb1, gates4);
    p3l<<<32, 256, 0, stream>>>(gates4, gates_pre, hnew, c_ws, xb2, t);
    p4m<<<204, 64, 0, stream>>>(dseq, xb2, d1a_pre, d1a_out, t);
  }

  // ---- mask decode (192/C chunks of C bt) — overwrites the out-scratch arena, reads only d1a_out (ws)
  for (int btbase=0; btbase<192; btbase+=C){
    md3_deconv<<<dim3(C,2,13), 256, 0, stream>>>(d1a_out, btbase, m1c, Wt3, dconv3_b, bnm2_g, bnm2_b);
    md2_deconv<<<dim3(C,196), 256, 0, stream>>>(m1c, m2b, Wt2, dconv2_b, bnm1_g, bnm1_b);
    md1_direct<<<dim3(C,49), 256, 0, stream>>>(m2b, m3b, dconv1_w, dconv1_b);
    k_resize<<<dim3(C,352), 256, 0, stream>>>(m3b, out_mask, btbase);
  }
}